// Round 1
// baseline (4100.987 us; speedup 1.0000x reference)
//
#include <hip/hip_runtime.h>

// Problem constants (fixed by the reference)
#define NN   507904          // nodes = 8192*62
#define NE   4063232         // edges = NN*8
#define NG   8192            // graphs
#define NPG  62              // nodes per graph
#define NBLK 1984            // NN/256, exact

// ws layout in floats
#define R_ELEMS   (NN * 64)                 // 32,505,856
#define OFF_R     0
#define OFF_AGG   (R_ELEMS)                 // 32,505,856
#define OFF_PART  (2 * R_ELEMS)             // 65,011,712
#define PART_FL   (NBLK * 128)              // 253,952
#define OFF_WT    (OFF_PART + PART_FL)      // 65,265,664
// wT: w1aT(64x4=256) w1bT(4096) w2aT(4096) w2bT(4096) w3aT(4096) w3bT(4096)
#define WT_W1A 0
#define WT_W1B 256
#define WT_W2A 4352
#define WT_W2B 8448
#define WT_W3A 12544
#define WT_W3B 16640
#define OFF_SS    (OFF_WT + 20736)          // 65,286,400 ; 3 layers x 128 floats
// total floats 65,286,784 -> 261,147,136 bytes of ws

// ---------------------------------------------------------------- transpose
__global__ __launch_bounds__(256) void transpose6(
    const float* __restrict__ w1a, const float* __restrict__ w1b,
    const float* __restrict__ w2a, const float* __restrict__ w2b,
    const float* __restrict__ w3a, const float* __restrict__ w3b,
    float* __restrict__ wt) {
  const float* src; float* dst; int rows, cols;
  switch (blockIdx.x) {
    case 0: src = w1a; dst = wt + WT_W1A; rows = 4;  cols = 64; break;
    case 1: src = w1b; dst = wt + WT_W1B; rows = 64; cols = 64; break;
    case 2: src = w2a; dst = wt + WT_W2A; rows = 64; cols = 64; break;
    case 3: src = w2b; dst = wt + WT_W2B; rows = 64; cols = 64; break;
    case 4: src = w3a; dst = wt + WT_W3A; rows = 64; cols = 64; break;
    default: src = w3b; dst = wt + WT_W3B; rows = 64; cols = 64; break;
  }
  for (int i = threadIdx.x; i < rows * cols; i += blockDim.x) {
    int r = i / cols, c = i % cols;
    dst[c * rows + r] = src[i];   // dst[o][k] = src[k][o]
  }
}

// ---------------------------------------------------------------- scatter C=4
__global__ __launch_bounds__(256) void scatter1(
    const float4* __restrict__ x, const int* __restrict__ src,
    const int* __restrict__ dst, float* __restrict__ agg) {
  int e = blockIdx.x * 256 + threadIdx.x;          // grid exact: NE/256
  int s = src[e], d = dst[e];
  float4 v = x[s];
  unsafeAtomicAdd(&agg[d * 4 + 0], v.x);
  unsafeAtomicAdd(&agg[d * 4 + 1], v.y);
  unsafeAtomicAdd(&agg[d * 4 + 2], v.z);
  unsafeAtomicAdd(&agg[d * 4 + 3], v.w);
}

// ---------------------------------------------------------------- scatter C=64
// one wave per edge, lane = channel; applies previous layer's BN affine on read
__global__ __launch_bounds__(256) void scatter64(
    const float* __restrict__ h, const int* __restrict__ src,
    const int* __restrict__ dst, const float* __restrict__ ss,
    float* __restrict__ agg) {
  int lane = threadIdx.x & 63;
  int e = blockIdx.x * 4 + (threadIdx.x >> 6);     // grid exact: NE/4
  int s = src[e], d = dst[e];
  float v = fmaf(ss[lane], h[s * 64 + lane], ss[64 + lane]);
  unsafeAtomicAdd(&agg[d * 64 + lane], v);
}

// ---------------------------------------------------------------- MLP + stats
// thread-per-node; t,z in registers; W^T read via wave-uniform loads.
// Epilogue: stage tile in swizzled LDS -> coalesced stores + BN partial sums.
template <int IN, bool SS>
__global__ __launch_bounds__(256) void mlp(
    const float* xin, const float* __restrict__ agg,
    const float* __restrict__ ssin,
    const float* __restrict__ waT, const float* __restrict__ ba,
    const float* __restrict__ wbT, const float* __restrict__ bb,
    float* rout, float* __restrict__ part) {
  __shared__ float tile[256 * 64];                 // 64 KiB, reused for reduce
  const int tid = threadIdx.x;
  const int node = blockIdx.x * 256 + tid;

  float t[IN];
  {
    const float4* x4 = (const float4*)xin + (size_t)node * (IN / 4);
    const float4* a4 = (const float4*)agg + (size_t)node * (IN / 4);
#pragma unroll
    for (int c4 = 0; c4 < IN / 4; ++c4) {
      float4 xv = x4[c4], av = a4[c4];
      if (SS) {
        t[4 * c4 + 0] = fmaf(ssin[4 * c4 + 0], xv.x, ssin[64 + 4 * c4 + 0]) + av.x;
        t[4 * c4 + 1] = fmaf(ssin[4 * c4 + 1], xv.y, ssin[64 + 4 * c4 + 1]) + av.y;
        t[4 * c4 + 2] = fmaf(ssin[4 * c4 + 2], xv.z, ssin[64 + 4 * c4 + 2]) + av.z;
        t[4 * c4 + 3] = fmaf(ssin[4 * c4 + 3], xv.w, ssin[64 + 4 * c4 + 3]) + av.w;
      } else {
        t[4 * c4 + 0] = xv.x + av.x;
        t[4 * c4 + 1] = xv.y + av.y;
        t[4 * c4 + 2] = xv.z + av.z;
        t[4 * c4 + 3] = xv.w + av.w;
      }
    }
  }

  float z[64];
#pragma unroll
  for (int o = 0; o < 64; ++o) {
    float a = ba[o];
#pragma unroll
    for (int c = 0; c < IN; ++c) a = fmaf(t[c], waT[o * IN + c], a);
    z[o] = fmaxf(a, 0.0f);
  }

#pragma unroll
  for (int o = 0; o < 64; ++o) {
    float a = bb[o];
#pragma unroll
    for (int k = 0; k < 64; ++k) a = fmaf(z[k], wbT[o * 64 + k], a);
    // rotate-swizzle: bank = (o+tid)%32 varies with lane -> conflict-free
    tile[(tid << 6) | ((o + tid) & 63)] = fmaxf(a, 0.0f);
  }
  __syncthreads();

  const int lane = tid & 63, wid = tid >> 6;
  const int nbase = blockIdx.x * 256 + wid * 64;
  float s = 0.f, q = 0.f;
#pragma unroll 8
  for (int n = 0; n < 64; ++n) {
    int row = wid * 64 + n;
    float v = tile[(row << 6) | ((lane + row) & 63)];
    rout[(size_t)(nbase + n) * 64 + lane] = v;     // coalesced 256B/wave
    s += v; q += v * v;
  }
  __syncthreads();
  tile[tid] = s; tile[256 + tid] = q;
  __syncthreads();
  if (tid < 128) {
    int col = tid & 63, which = tid >> 6;          // 0: sum, 1: sumsq
    const float* b0 = &tile[which * 256];
    part[blockIdx.x * 128 + tid] =
        b0[col] + b0[64 + col] + b0[128 + col] + b0[192 + col];
  }
}

// ---------------------------------------------------------------- BN finalize
__global__ __launch_bounds__(128) void finalize(
    const float* __restrict__ part, const float* __restrict__ gma,
    const float* __restrict__ bta, float* __restrict__ ss) {
  __shared__ double sh[128];
  int tid = threadIdx.x;                            // 128 threads
  double a = 0.0;
  for (int b = 0; b < NBLK; ++b) a += (double)part[b * 128 + tid];
  sh[tid] = a;
  __syncthreads();
  if (tid < 64) {
    double mean = sh[tid] / (double)NN;
    double var = sh[64 + tid] / (double)NN - mean * mean;
    double sc = (double)gma[tid] / sqrt(var + 1e-5);
    ss[tid] = (float)sc;
    ss[64 + tid] = (float)((double)bta[tid] - mean * sc);
  }
}

// ---------------------------------------------------------------- pool + fc
__global__ __launch_bounds__(64) void pool_fc(
    const float* __restrict__ r3, const float* __restrict__ ss,
    const float* __restrict__ wfc, const float* __restrict__ bfc,
    float* __restrict__ out) {
  int g = blockIdx.x, c = threadIdx.x;
  const float* base = r3 + (size_t)g * NPG * 64;
  float s = 0.f;
#pragma unroll
  for (int n = 0; n < NPG; ++n) s += base[n * 64 + c];
  float pooled = fmaf(ss[c], s, (float)NPG * ss[64 + c]);
#pragma unroll
  for (int j = 0; j < 3; ++j) {
    float v = pooled * wfc[c * 3 + j];
    for (int m = 32; m; m >>= 1) v += __shfl_xor(v, m);
    if (c == 0) out[g * 3 + j] = v + bfc[j];
  }
}

// ---------------------------------------------------------------- launch
extern "C" void kernel_launch(void* const* d_in, const int* in_sizes, int n_in,
                              void* d_out, int out_size, void* d_ws, size_t ws_size,
                              hipStream_t stream) {
  const float* x    = (const float*)d_in[0];
  const int*   src  = (const int*)d_in[1];
  const int*   dst  = (const int*)d_in[2];
  const float* W1a = (const float*)d_in[4],  *b1a = (const float*)d_in[5];
  const float* W1b = (const float*)d_in[6],  *b1b = (const float*)d_in[7];
  const float* g1  = (const float*)d_in[8],  *be1 = (const float*)d_in[9];
  const float* W2a = (const float*)d_in[10], *b2a = (const float*)d_in[11];
  const float* W2b = (const float*)d_in[12], *b2b = (const float*)d_in[13];
  const float* g2  = (const float*)d_in[14], *be2 = (const float*)d_in[15];
  const float* W3a = (const float*)d_in[16], *b3a = (const float*)d_in[17];
  const float* W3b = (const float*)d_in[18], *b3b = (const float*)d_in[19];
  const float* g3  = (const float*)d_in[20], *be3 = (const float*)d_in[21];
  const float* Wfc = (const float*)d_in[22], *bfc = (const float*)d_in[23];

  float* ws   = (float*)d_ws;
  float* R    = ws + OFF_R;
  float* AGG  = ws + OFF_AGG;
  float* PART = ws + OFF_PART;
  float* WT   = ws + OFF_WT;
  float* SS   = ws + OFF_SS;   // 3 layers x (scale[64], shift[64])

  transpose6<<<6, 256, 0, stream>>>(W1a, W1b, W2a, W2b, W3a, W3b, WT);

  // ---- layer 1 (C_in = 4)
  hipMemsetAsync(AGG, 0, (size_t)NN * 4 * sizeof(float), stream);
  scatter1<<<NE / 256, 256, 0, stream>>>((const float4*)x, src, dst, AGG);
  mlp<4, false><<<NBLK, 256, 0, stream>>>(x, AGG, nullptr, WT + WT_W1A, b1a,
                                          WT + WT_W1B, b1b, R, PART);
  finalize<<<1, 128, 0, stream>>>(PART, g1, be1, SS + 0);

  // ---- layer 2
  hipMemsetAsync(AGG, 0, (size_t)NN * 64 * sizeof(float), stream);
  scatter64<<<NE / 4, 256, 0, stream>>>(R, src, dst, SS + 0, AGG);
  mlp<64, true><<<NBLK, 256, 0, stream>>>(R, AGG, SS + 0, WT + WT_W2A, b2a,
                                          WT + WT_W2B, b2b, R, PART);
  finalize<<<1, 128, 0, stream>>>(PART, g2, be2, SS + 128);

  // ---- layer 3
  hipMemsetAsync(AGG, 0, (size_t)NN * 64 * sizeof(float), stream);
  scatter64<<<NE / 4, 256, 0, stream>>>(R, src, dst, SS + 128, AGG);
  mlp<64, true><<<NBLK, 256, 0, stream>>>(R, AGG, SS + 128, WT + WT_W3A, b3a,
                                          WT + WT_W3B, b3b, R, PART);
  finalize<<<1, 128, 0, stream>>>(PART, g3, be3, SS + 256);

  // ---- pool + classifier
  pool_fc<<<NG, 64, 0, stream>>>(R, SS + 256, Wfc, bfc, (float*)d_out);
}

// Round 2
// 2352.215 us; speedup vs baseline: 1.7435x; 1.7435x over previous
//
#include <hip/hip_runtime.h>
#include <hip/hip_bf16.h>

// Problem constants (fixed by the reference)
#define NN   507904          // nodes = 8192*62
#define NE   4063232         // edges = NN*8
#define NG   8192            // graphs
#define NPG  62              // nodes per graph
#define NBLK 1984            // NN/256, exact

// ---------------------------------------------------------------- ws layout (float/int units, 4B each)
#define OFF_R     0                         // NN*64 fp32 features
#define OFF_AGGBF (OFF_R + NN * 64)         // NN*64 bf16 = NN*32 slots
#define OFF_CSR   (OFF_AGGBF + NN * 32)     // NE ints (compact CSR src lists)
#define OFF_CNT   (OFF_CSR + NE)            // NN ints (in-degree)
#define OFF_OFFA  (OFF_CNT + NN)            // NN ints (CSR start offsets)
#define OFF_CUR   (OFF_OFFA + NN)           // NN ints (placement cursors)
#define OFF_BSUM  (OFF_CUR + NN)            // NBLK ints
#define OFF_BSCAN (OFF_BSUM + NBLK)         // NBLK ints
#define OFF_PART  (OFF_BSCAN + NBLK)        // NBLK*128 floats (BN partials)
#define OFF_WT    (OFF_PART + NBLK * 128)   // transposed weights
#define WT_W1A 0
#define WT_W1B 256
#define WT_W2A 4352
#define WT_W2B 8448
#define WT_W3A 12544
#define WT_W3B 16640
#define OFF_SS    (OFF_WT + 20736)          // 3 layers x (scale[64], shift[64])
// total = 54,624,768 units = 218.5 MB  (< 261 MB known-good)

__device__ __forceinline__ void bf2f(unsigned u, float& a, float& b) {
  union { unsigned i; float f; } lo, hi;
  lo.i = u << 16; hi.i = u & 0xFFFF0000u;
  a = lo.f; b = hi.f;
}

// ---------------------------------------------------------------- transpose
__global__ __launch_bounds__(256) void transpose6(
    const float* __restrict__ w1a, const float* __restrict__ w1b,
    const float* __restrict__ w2a, const float* __restrict__ w2b,
    const float* __restrict__ w3a, const float* __restrict__ w3b,
    float* __restrict__ wt) {
  const float* src; float* dst; int rows, cols;
  switch (blockIdx.x) {
    case 0: src = w1a; dst = wt + WT_W1A; rows = 4;  cols = 64; break;
    case 1: src = w1b; dst = wt + WT_W1B; rows = 64; cols = 64; break;
    case 2: src = w2a; dst = wt + WT_W2A; rows = 64; cols = 64; break;
    case 3: src = w2b; dst = wt + WT_W2B; rows = 64; cols = 64; break;
    case 4: src = w3a; dst = wt + WT_W3A; rows = 64; cols = 64; break;
    default: src = w3b; dst = wt + WT_W3B; rows = 64; cols = 64; break;
  }
  for (int i = threadIdx.x; i < rows * cols; i += blockDim.x) {
    int r = i / cols, c = i % cols;
    dst[c * rows + r] = src[i];   // dst[o][k] = src[k][o]
  }
}

// ---------------------------------------------------------------- CSR build
__global__ __launch_bounds__(256) void hist(const int* __restrict__ dst,
                                            int* __restrict__ cnt) {
  int e = blockIdx.x * 256 + threadIdx.x;     // grid exact NE/256
  atomicAdd(&cnt[dst[e]], 1);
}

// per-block exclusive scan of cnt -> offa(local), block totals -> bsum
__global__ __launch_bounds__(256) void scanA(const int* __restrict__ cnt,
                                             int* __restrict__ offa,
                                             int* __restrict__ bsum) {
  __shared__ int sh[256];
  int tid = threadIdx.x, i = blockIdx.x * 256 + tid;
  int v = cnt[i];
  sh[tid] = v; __syncthreads();
  for (int s = 1; s < 256; s <<= 1) {
    int add = (tid >= s) ? sh[tid - s] : 0;
    __syncthreads();
    sh[tid] += add;
    __syncthreads();
  }
  offa[i] = sh[tid] - v;                       // exclusive within block
  if (tid == 255) bsum[blockIdx.x] = sh[255];
}

// exclusive scan of the 1984 block sums
__global__ __launch_bounds__(256) void scanB(const int* __restrict__ bsum,
                                             int* __restrict__ bscan) {
  __shared__ int sh[256];
  int tid = threadIdx.x;
  int l[8]; int s = 0;
  if (tid < NBLK / 8) {
#pragma unroll
    for (int k = 0; k < 8; ++k) { l[k] = s; s += bsum[tid * 8 + k]; }
  }
  sh[tid] = s; __syncthreads();
  for (int st = 1; st < 256; st <<= 1) {
    int add = (tid >= st) ? sh[tid - st] : 0;
    __syncthreads();
    sh[tid] += add;
    __syncthreads();
  }
  int base = sh[tid] - s;                      // exclusive over threads
  if (tid < NBLK / 8) {
#pragma unroll
    for (int k = 0; k < 8; ++k) bscan[tid * 8 + k] = base + l[k];
  }
}

__global__ __launch_bounds__(256) void scanC(int* __restrict__ offa,
                                             const int* __restrict__ bscan,
                                             int* __restrict__ cur) {
  int i = blockIdx.x * 256 + threadIdx.x;
  int o = offa[i] + bscan[blockIdx.x];
  offa[i] = o;
  cur[i] = o;
}

__global__ __launch_bounds__(256) void place(const int* __restrict__ src,
                                             const int* __restrict__ dst,
                                             int* __restrict__ cur,
                                             int* __restrict__ csr) {
  int e = blockIdx.x * 256 + threadIdx.x;
  int p = atomicAdd(&cur[dst[e]], 1);
  csr[p] = src[e];
}

// ---------------------------------------------------------------- gather, layer 1 (C=4)
// t = x[self] + sum_{j->i} x[j], fp32 out
__global__ __launch_bounds__(256) void gather1(
    const float4* __restrict__ x, const int* __restrict__ csr,
    const int* __restrict__ offa, const int* __restrict__ cnt,
    float4* __restrict__ tout) {
  int n = blockIdx.x * 256 + threadIdx.x;      // grid exact NN/256
  float4 a = x[n];
  int off = offa[n], deg = cnt[n];
  const int* cp = csr + off;
  int j = 0;
  for (; j + 4 <= deg; j += 4) {
    int s0 = cp[j], s1 = cp[j + 1], s2 = cp[j + 2], s3 = cp[j + 3];
    float4 v0 = x[s0], v1 = x[s1], v2 = x[s2], v3 = x[s3];
    a.x += v0.x + v1.x + v2.x + v3.x;
    a.y += v0.y + v1.y + v2.y + v3.y;
    a.z += v0.z + v1.z + v2.z + v3.z;
    a.w += v0.w + v1.w + v2.w + v3.w;
  }
  for (; j < deg; ++j) {
    float4 v = x[cp[j]];
    a.x += v.x; a.y += v.y; a.z += v.z; a.w += v.w;
  }
  tout[n] = a;
}

// ---------------------------------------------------------------- gather, layers 2/3 (C=64)
// wave per node, lane = channel; t = affine(h[self]) + sum affine(h[j]); bf16 out
__global__ __launch_bounds__(256) void gather64(
    const float* __restrict__ h, const int* __restrict__ csr,
    const int* __restrict__ offa, const int* __restrict__ cnt,
    const float* __restrict__ ss, __hip_bfloat16* __restrict__ tout) {
  const int c = threadIdx.x & 63;
  const int n = blockIdx.x * 4 + (threadIdx.x >> 6);   // grid exact NN/4
  const float sc = ss[c], sf = ss[64 + c];
  float acc = fmaf(sc, h[(size_t)n * 64 + c], sf);
  const int off = offa[n], deg = cnt[n];
  const int* cp = csr + off;
  int j = 0;
  for (; j + 4 <= deg; j += 4) {
    int s0 = cp[j], s1 = cp[j + 1], s2 = cp[j + 2], s3 = cp[j + 3];
    float v0 = h[(size_t)s0 * 64 + c];
    float v1 = h[(size_t)s1 * 64 + c];
    float v2 = h[(size_t)s2 * 64 + c];
    float v3 = h[(size_t)s3 * 64 + c];
    acc += fmaf(sc, v0, sf) + fmaf(sc, v1, sf) + fmaf(sc, v2, sf) + fmaf(sc, v3, sf);
  }
  for (; j < deg; ++j)
    acc += fmaf(sc, h[(size_t)cp[j] * 64 + c], sf);
  tout[(size_t)n * 64 + c] = __float2bfloat16(acc);
}

// ---------------------------------------------------------------- MLP + stats
// thread-per-node; t,z in registers; W^T read via wave-uniform loads.
template <int IN, bool BF>
__global__ __launch_bounds__(256) void mlp(
    const void* __restrict__ tin,
    const float* __restrict__ waT, const float* __restrict__ ba,
    const float* __restrict__ wbT, const float* __restrict__ bb,
    float* __restrict__ rout, float* __restrict__ part) {
  __shared__ float tile[256 * 64];                 // 64 KiB, reused for reduce
  const int tid = threadIdx.x;
  const int node = blockIdx.x * 256 + tid;

  float t[IN];
  if constexpr (BF) {
    const uint4* tb = (const uint4*)tin + (size_t)node * 8;   // IN==64
#pragma unroll
    for (int k = 0; k < 8; ++k) {
      uint4 u = tb[k];
      bf2f(u.x, t[8 * k + 0], t[8 * k + 1]);
      bf2f(u.y, t[8 * k + 2], t[8 * k + 3]);
      bf2f(u.z, t[8 * k + 4], t[8 * k + 5]);
      bf2f(u.w, t[8 * k + 6], t[8 * k + 7]);
    }
  } else {
    const float4* a4 = (const float4*)tin + node;             // IN==4
    float4 v = a4[0];
    t[0] = v.x; t[1] = v.y; t[2] = v.z; t[3] = v.w;
  }

  float z[64];
#pragma unroll
  for (int o = 0; o < 64; ++o) {
    float a = ba[o];
#pragma unroll
    for (int c = 0; c < IN; ++c) a = fmaf(t[c], waT[o * IN + c], a);
    z[o] = fmaxf(a, 0.0f);
  }

#pragma unroll
  for (int o = 0; o < 64; ++o) {
    float a = bb[o];
#pragma unroll
    for (int k = 0; k < 64; ++k) a = fmaf(z[k], wbT[o * 64 + k], a);
    // rotate-swizzle: conflict-free staging
    tile[(tid << 6) | ((o + tid) & 63)] = fmaxf(a, 0.0f);
  }
  __syncthreads();

  const int lane = tid & 63, wid = tid >> 6;
  const int nbase = blockIdx.x * 256 + wid * 64;
  float s = 0.f, q = 0.f;
#pragma unroll 8
  for (int n = 0; n < 64; ++n) {
    int row = wid * 64 + n;
    float v = tile[(row << 6) | ((lane + row) & 63)];
    rout[(size_t)(nbase + n) * 64 + lane] = v;     // coalesced 256B/wave
    s += v; q += v * v;
  }
  __syncthreads();
  tile[tid] = s; tile[256 + tid] = q;
  __syncthreads();
  if (tid < 128) {
    int col = tid & 63, which = tid >> 6;          // 0: sum, 1: sumsq
    const float* b0 = &tile[which * 256];
    part[blockIdx.x * 128 + tid] =
        b0[col] + b0[64 + col] + b0[128 + col] + b0[192 + col];
  }
}

// ---------------------------------------------------------------- BN finalize
__global__ __launch_bounds__(1024) void finalize(
    const float* __restrict__ part, const float* __restrict__ gma,
    const float* __restrict__ bta, float* __restrict__ ss) {
  __shared__ double sh[1024];
  __shared__ double tot[128];
  int tid = threadIdx.x;
  int col = tid & 127, chunk = tid >> 7;           // 8 chunks
  double a = 0.0;
  for (int b = chunk; b < NBLK; b += 8) a += (double)part[b * 128 + col];
  sh[tid] = a;
  __syncthreads();
  if (tid < 128) {
    double v = 0.0;
#pragma unroll
    for (int k = 0; k < 8; ++k) v += sh[k * 128 + tid];
    tot[tid] = v;
  }
  __syncthreads();
  if (tid < 64) {
    double mean = tot[tid] / (double)NN;
    double var = tot[64 + tid] / (double)NN - mean * mean;
    double sc = (double)gma[tid] / sqrt(var + 1e-5);
    ss[tid] = (float)sc;
    ss[64 + tid] = (float)((double)bta[tid] - mean * sc);
  }
}

// ---------------------------------------------------------------- pool + fc
__global__ __launch_bounds__(64) void pool_fc(
    const float* __restrict__ r3, const float* __restrict__ ss,
    const float* __restrict__ wfc, const float* __restrict__ bfc,
    float* __restrict__ out) {
  int g = blockIdx.x, c = threadIdx.x;
  const float* base = r3 + (size_t)g * NPG * 64;
  float s = 0.f;
#pragma unroll
  for (int n = 0; n < NPG; ++n) s += base[n * 64 + c];
  float pooled = fmaf(ss[c], s, (float)NPG * ss[64 + c]);
#pragma unroll
  for (int j = 0; j < 3; ++j) {
    float v = pooled * wfc[c * 3 + j];
    for (int m = 32; m; m >>= 1) v += __shfl_xor(v, m);
    if (c == 0) out[g * 3 + j] = v + bfc[j];
  }
}

// ---------------------------------------------------------------- launch
extern "C" void kernel_launch(void* const* d_in, const int* in_sizes, int n_in,
                              void* d_out, int out_size, void* d_ws, size_t ws_size,
                              hipStream_t stream) {
  const float* x    = (const float*)d_in[0];
  const int*   srcE = (const int*)d_in[1];
  const int*   dstE = (const int*)d_in[2];
  const float* W1a = (const float*)d_in[4],  *b1a = (const float*)d_in[5];
  const float* W1b = (const float*)d_in[6],  *b1b = (const float*)d_in[7];
  const float* g1  = (const float*)d_in[8],  *be1 = (const float*)d_in[9];
  const float* W2a = (const float*)d_in[10], *b2a = (const float*)d_in[11];
  const float* W2b = (const float*)d_in[12], *b2b = (const float*)d_in[13];
  const float* g2  = (const float*)d_in[14], *be2 = (const float*)d_in[15];
  const float* W3a = (const float*)d_in[16], *b3a = (const float*)d_in[17];
  const float* W3b = (const float*)d_in[18], *b3b = (const float*)d_in[19];
  const float* g3  = (const float*)d_in[20], *be3 = (const float*)d_in[21];
  const float* Wfc = (const float*)d_in[22], *bfc = (const float*)d_in[23];

  float* ws = (float*)d_ws;
  float* R     = ws + OFF_R;
  void*  AGGBF = (void*)(ws + OFF_AGGBF);
  int*   CSR   = (int*)(ws + OFF_CSR);
  int*   CNT   = (int*)(ws + OFF_CNT);
  int*   OFFA  = (int*)(ws + OFF_OFFA);
  int*   CUR   = (int*)(ws + OFF_CUR);
  int*   BSUM  = (int*)(ws + OFF_BSUM);
  int*   BSCAN = (int*)(ws + OFF_BSCAN);
  float* PART  = ws + OFF_PART;
  float* WT    = ws + OFF_WT;
  float* SS    = ws + OFF_SS;

  transpose6<<<6, 256, 0, stream>>>(W1a, W1b, W2a, W2b, W3a, W3b, WT);

  // ---- CSR build (once per call)
  hipMemsetAsync(CNT, 0, NN * sizeof(int), stream);
  hist<<<NE / 256, 256, 0, stream>>>(dstE, CNT);
  scanA<<<NBLK, 256, 0, stream>>>(CNT, OFFA, BSUM);
  scanB<<<1, 256, 0, stream>>>(BSUM, BSCAN);
  scanC<<<NBLK, 256, 0, stream>>>(OFFA, BSCAN, CUR);
  place<<<NE / 256, 256, 0, stream>>>(srcE, dstE, CUR, CSR);

  // ---- layer 1 (C_in = 4)
  gather1<<<NN / 256, 256, 0, stream>>>((const float4*)x, CSR, OFFA, CNT,
                                        (float4*)AGGBF);
  mlp<4, false><<<NBLK, 256, 0, stream>>>(AGGBF, WT + WT_W1A, b1a,
                                          WT + WT_W1B, b1b, R, PART);
  finalize<<<1, 1024, 0, stream>>>(PART, g1, be1, SS + 0);

  // ---- layer 2
  gather64<<<NN / 4, 256, 0, stream>>>(R, CSR, OFFA, CNT, SS + 0,
                                       (__hip_bfloat16*)AGGBF);
  mlp<64, true><<<NBLK, 256, 0, stream>>>(AGGBF, WT + WT_W2A, b2a,
                                          WT + WT_W2B, b2b, R, PART);
  finalize<<<1, 1024, 0, stream>>>(PART, g2, be2, SS + 128);

  // ---- layer 3
  gather64<<<NN / 4, 256, 0, stream>>>(R, CSR, OFFA, CNT, SS + 128,
                                       (__hip_bfloat16*)AGGBF);
  mlp<64, true><<<NBLK, 256, 0, stream>>>(AGGBF, WT + WT_W3A, b3a,
                                          WT + WT_W3B, b3b, R, PART);
  finalize<<<1, 1024, 0, stream>>>(PART, g3, be3, SS + 256);

  // ---- pool + classifier
  pool_fc<<<NG, 64, 0, stream>>>(R, SS + 256, Wfc, bfc, (float*)d_out);
}

// Round 3
// 1309.518 us; speedup vs baseline: 3.1317x; 1.7962x over previous
//
#include <hip/hip_runtime.h>
#include <hip/hip_bf16.h>

// Problem constants (fixed by the reference)
#define NN   507904          // nodes = 8192*62
#define NE   4063232         // edges = NN*8
#define NG   8192            // graphs
#define NPG  62              // nodes per graph
#define NBLK 1984            // NN/256 (scan grid)
#define NBLKM 992            // NN/512 (mlp grid)

// ---------------------------------------------------------------- ws layout (4B units)
#define OFF_R     0                          // NN*64 fp32 features
#define OFF_AGGBF (OFF_R + NN * 64)          // t: bf16 NN*64 (or fp32 NN*4 for L1)
#define OFF_CSR   (OFF_AGGBF + NN * 32)      // NE ints
#define OFF_CNT   (OFF_CSR + NE)             // NN ints
#define OFF_OFFA  (OFF_CNT + NN)             // NN ints
#define OFF_CUR   (OFF_OFFA + NN)            // NN ints
#define OFF_BSUM  (OFF_CUR + NN)             // NBLK ints
#define OFF_BSCAN (OFF_BSUM + NBLK)          // NBLK ints
#define OFF_PART  (OFF_BSCAN + NBLK)         // NBLKM*128 floats
#define OFF_WT    (OFF_PART + NBLKM * 128)   // fp32 W1a^T: 256 floats
#define OFF_WTB   (OFF_WT + 256)             // bf16 transposed weights: 20480 bf16
#define OFF_SS    (OFF_WTB + 10240)          // 3 x (scale[64], shift[64])
// total = 54,487,552 units = 218 MB

// bf16 weight offsets (ushort units)
#define WB_W1B 0
#define WB_W2A 4096
#define WB_W2B 8192
#define WB_W3A 12288
#define WB_W3B 16384

typedef __attribute__((ext_vector_type(8))) short short8;
typedef __attribute__((ext_vector_type(4))) float f32x4;
typedef unsigned short ushort_t;

__device__ __forceinline__ ushort_t f2bf_bits(float f) {
  union { float f; unsigned u; } x; x.f = f;
  unsigned r = x.u + 0x7FFF + ((x.u >> 16) & 1);
  return (ushort_t)(r >> 16);
}
__device__ __forceinline__ void bf2f(unsigned u, float& a, float& b) {
  union { unsigned i; float f; } lo, hi;
  lo.i = u << 16; hi.i = u & 0xFFFF0000u;
  a = lo.f; b = hi.f;
}

// ---------------------------------------------------------------- weight prep
// block 0: W1a [4][64] -> fp32 [o][c] (WT). blocks 1-5: W -> bf16 [n][k] (WTB).
__global__ __launch_bounds__(256) void prep_weights(
    const float* __restrict__ w1a, const float* __restrict__ w1b,
    const float* __restrict__ w2a, const float* __restrict__ w2b,
    const float* __restrict__ w3a, const float* __restrict__ w3b,
    float* __restrict__ wt, ushort_t* __restrict__ wtb) {
  int b = blockIdx.x, tid = threadIdx.x;
  if (b == 0) {
    if (tid < 256) {
      int k = tid >> 6, n = tid & 63;          // src [4][64]
      wt[n * 4 + k] = w1a[tid];
    }
  } else {
    const float* s; ushort_t* d;
    switch (b) {
      case 1: s = w1b; d = wtb + WB_W1B; break;
      case 2: s = w2a; d = wtb + WB_W2A; break;
      case 3: s = w2b; d = wtb + WB_W2B; break;
      case 4: s = w3a; d = wtb + WB_W3A; break;
      default: s = w3b; d = wtb + WB_W3B; break;
    }
    for (int i = tid; i < 4096; i += 256) {
      int k = i >> 6, n = i & 63;              // src [k][n]
      d[n * 64 + k] = f2bf_bits(s[i]);         // dst [n][k]
    }
  }
}

// ---------------------------------------------------------------- CSR build
__global__ __launch_bounds__(256) void hist(const int* __restrict__ dst,
                                            int* __restrict__ cnt) {
  int e = blockIdx.x * 256 + threadIdx.x;
  atomicAdd(&cnt[dst[e]], 1);
}

__global__ __launch_bounds__(256) void scanA(const int* __restrict__ cnt,
                                             int* __restrict__ offa,
                                             int* __restrict__ bsum) {
  __shared__ int sh[256];
  int tid = threadIdx.x, i = blockIdx.x * 256 + tid;
  int v = cnt[i];
  sh[tid] = v; __syncthreads();
  for (int s = 1; s < 256; s <<= 1) {
    int add = (tid >= s) ? sh[tid - s] : 0;
    __syncthreads();
    sh[tid] += add;
    __syncthreads();
  }
  offa[i] = sh[tid] - v;
  if (tid == 255) bsum[blockIdx.x] = sh[255];
}

__global__ __launch_bounds__(256) void scanB(const int* __restrict__ bsum,
                                             int* __restrict__ bscan) {
  __shared__ int sh[256];
  int tid = threadIdx.x;
  int l[8]; int s = 0;
  if (tid < NBLK / 8) {
#pragma unroll
    for (int k = 0; k < 8; ++k) { l[k] = s; s += bsum[tid * 8 + k]; }
  }
  sh[tid] = s; __syncthreads();
  for (int st = 1; st < 256; st <<= 1) {
    int add = (tid >= st) ? sh[tid - st] : 0;
    __syncthreads();
    sh[tid] += add;
    __syncthreads();
  }
  int base = sh[tid] - s;
  if (tid < NBLK / 8) {
#pragma unroll
    for (int k = 0; k < 8; ++k) bscan[tid * 8 + k] = base + l[k];
  }
}

__global__ __launch_bounds__(256) void scanC(int* __restrict__ offa,
                                             const int* __restrict__ bscan,
                                             int* __restrict__ cur) {
  int i = blockIdx.x * 256 + threadIdx.x;
  int o = offa[i] + bscan[blockIdx.x];
  offa[i] = o;
  cur[i] = o;
}

__global__ __launch_bounds__(256) void place(const int* __restrict__ src,
                                             const int* __restrict__ dst,
                                             int* __restrict__ cur,
                                             int* __restrict__ csr) {
  int e = blockIdx.x * 256 + threadIdx.x;
  int p = atomicAdd(&cur[dst[e]], 1);
  csr[p] = src[e];
}

// ---------------------------------------------------------------- gather L1 (C=4)
__global__ __launch_bounds__(256) void gather1(
    const float4* __restrict__ x, const int* __restrict__ csr,
    const int* __restrict__ offa, const int* __restrict__ cnt,
    float4* __restrict__ tout) {
  int n = blockIdx.x * 256 + threadIdx.x;
  float4 a = x[n];
  int off = offa[n], deg = cnt[n];
  const int* cp = csr + off;
  int j = 0;
  for (; j + 4 <= deg; j += 4) {
    int s0 = cp[j], s1 = cp[j + 1], s2 = cp[j + 2], s3 = cp[j + 3];
    float4 v0 = x[s0], v1 = x[s1], v2 = x[s2], v3 = x[s3];
    a.x += v0.x + v1.x + v2.x + v3.x;
    a.y += v0.y + v1.y + v2.y + v3.y;
    a.z += v0.z + v1.z + v2.z + v3.z;
    a.w += v0.w + v1.w + v2.w + v3.w;
  }
  for (; j < deg; ++j) {
    float4 v = x[cp[j]];
    a.x += v.x; a.y += v.y; a.z += v.z; a.w += v.w;
  }
  tout[n] = a;
}

// ---------------------------------------------------------------- gather L2/3 (C=64)
__global__ __launch_bounds__(256) void gather64(
    const float* __restrict__ h, const int* __restrict__ csr,
    const int* __restrict__ offa, const int* __restrict__ cnt,
    const float* __restrict__ ss, __hip_bfloat16* __restrict__ tout) {
  const int c = threadIdx.x & 63;
  const int n = blockIdx.x * 4 + (threadIdx.x >> 6);
  const float sc = ss[c], sf = ss[64 + c];
  float acc = fmaf(sc, h[(size_t)n * 64 + c], sf);
  const int off = offa[n], deg = cnt[n];
  const int* cp = csr + off;
  int j = 0;
  for (; j + 4 <= deg; j += 4) {
    int s0 = cp[j], s1 = cp[j + 1], s2 = cp[j + 2], s3 = cp[j + 3];
    float v0 = h[(size_t)s0 * 64 + c];
    float v1 = h[(size_t)s1 * 64 + c];
    float v2 = h[(size_t)s2 * 64 + c];
    float v3 = h[(size_t)s3 * 64 + c];
    acc += fmaf(sc, v0, sf) + fmaf(sc, v1, sf) + fmaf(sc, v2, sf) + fmaf(sc, v3, sf);
  }
  for (; j < deg; ++j)
    acc += fmaf(sc, h[(size_t)cp[j] * 64 + c], sf);
  tout[(size_t)n * 64 + c] = __float2bfloat16(acc);
}

// ---------------------------------------------------------------- MFMA MLP
// 4 waves/block, 16 rows/wave, 8 iters -> 512 nodes/block. grid = 992.
// A-layout: A[m=lane&15][k=quad*8+j]; B from W^T[n][k]: n=lane&15;
// C/D: col=lane&15, row=quad*4+reg (m89/m91-verified mappings).
template <bool L1>
__global__ __launch_bounds__(256) void mlp_mfma(
    const void* __restrict__ tin,
    const ushort_t* __restrict__ WaTb,   // bf16 [n][k] (unused if L1)
    const float* __restrict__ WaTf,      // fp32 [o][c] (L1 only)
    const float* __restrict__ ba,
    const ushort_t* __restrict__ WbTb,   // bf16 [n][k]
    const float* __restrict__ bb,
    float* __restrict__ rout, float* __restrict__ part) {
  __shared__ __align__(16) ushort_t zt[4096];   // 4 waves x 16x64 bf16, XOR-swizzled
  __shared__ float red[512];
  __shared__ float wa_l1[320];                  // L1: WaT(256) + ba(64)
  const int tid = threadIdx.x;
  const int wave = tid >> 6, lane = tid & 63;
  const int col = lane & 15, quad = lane >> 4;

  if (L1) {
    if (tid < 256) wa_l1[tid] = WaTf[tid];
    if (tid < 64) wa_l1[256 + tid] = ba[tid];
    __syncthreads();
  }

  // B-fragments in registers for the whole kernel
  short8 bWa[2][4], bWb[2][4];
#pragma unroll
  for (int k0 = 0; k0 < 2; ++k0)
#pragma unroll
    for (int nt = 0; nt < 4; ++nt) {
      if (!L1) bWa[k0][nt] = *(const short8*)(WaTb + (nt * 16 + col) * 64 + k0 * 32 + quad * 8);
      bWb[k0][nt] = *(const short8*)(WbTb + (nt * 16 + col) * 64 + k0 * 32 + quad * 8);
    }
  float ba_n[4], bb_n[4];
#pragma unroll
  for (int nt = 0; nt < 4; ++nt) {
    if (!L1) ba_n[nt] = ba[nt * 16 + col];
    bb_n[nt] = bb[nt * 16 + col];
  }

  const int wbase = wave * 1024;
  float scol[4] = {0, 0, 0, 0}, qcol[4] = {0, 0, 0, 0};

  for (int it = 0; it < 8; ++it) {
    const int tile = blockIdx.x * 512 + it * 64 + wave * 16;
    short8 az0, az1;

    if constexpr (L1) {
      // z computed directly in A-frag layout (K=4 VALU GEMM)
      float4 t4 = ((const float4*)tin)[tile + col];
#pragma unroll
      for (int k0 = 0; k0 < 2; ++k0) {
        short8 az;
#pragma unroll
        for (int j = 0; j < 8; ++j) {
          int o = k0 * 32 + quad * 8 + j;
          float z = wa_l1[256 + o];
          z = fmaf(t4.x, wa_l1[o * 4 + 0], z);
          z = fmaf(t4.y, wa_l1[o * 4 + 1], z);
          z = fmaf(t4.z, wa_l1[o * 4 + 2], z);
          z = fmaf(t4.w, wa_l1[o * 4 + 3], z);
          az[j] = (short)f2bf_bits(fmaxf(z, 0.0f));
        }
        if (k0 == 0) az0 = az; else az1 = az;
      }
    } else {
      const ushort_t* tb = (const ushort_t*)tin;
      short8 a0 = *(const short8*)(tb + (size_t)(tile + col) * 64 + quad * 8);
      short8 a1 = *(const short8*)(tb + (size_t)(tile + col) * 64 + 32 + quad * 8);
      f32x4 acc1[4];
#pragma unroll
      for (int nt = 0; nt < 4; ++nt) acc1[nt] = (f32x4){0.f, 0.f, 0.f, 0.f};
#pragma unroll
      for (int nt = 0; nt < 4; ++nt) {
        acc1[nt] = __builtin_amdgcn_mfma_f32_16x16x32_bf16(a0, bWa[0][nt], acc1[nt], 0, 0, 0);
        acc1[nt] = __builtin_amdgcn_mfma_f32_16x16x32_bf16(a1, bWa[1][nt], acc1[nt], 0, 0, 0);
      }
      // relu -> bf16 -> swizzled LDS (C-layout write)
#pragma unroll
      for (int nt = 0; nt < 4; ++nt) {
        int oblk = nt * 2 + (col >> 3);
#pragma unroll
        for (int r = 0; r < 4; ++r) {
          int row = quad * 4 + r;
          float z = fmaxf(acc1[nt][r] + ba_n[nt], 0.0f);
          zt[wbase + row * 64 + (((oblk ^ (row & 7)) << 3) | (col & 7))] = f2bf_bits(z);
        }
      }
      // A-layout read (wave-private region; DS ops are wave-ordered)
      int m = col;
      az0 = *(const short8*)&zt[wbase + m * 64 + ((quad ^ (m & 7)) << 3)];
      az1 = *(const short8*)&zt[wbase + m * 64 + (((4 + quad) ^ (m & 7)) << 3)];
    }

    f32x4 acc2[4];
#pragma unroll
    for (int nt = 0; nt < 4; ++nt) acc2[nt] = (f32x4){0.f, 0.f, 0.f, 0.f};
#pragma unroll
    for (int nt = 0; nt < 4; ++nt) {
      acc2[nt] = __builtin_amdgcn_mfma_f32_16x16x32_bf16(az0, bWb[0][nt], acc2[nt], 0, 0, 0);
      acc2[nt] = __builtin_amdgcn_mfma_f32_16x16x32_bf16(az1, bWb[1][nt], acc2[nt], 0, 0, 0);
    }
#pragma unroll
    for (int nt = 0; nt < 4; ++nt) {
#pragma unroll
      for (int r = 0; r < 4; ++r) {
        int row = tile + quad * 4 + r;
        float v = fmaxf(acc2[nt][r] + bb_n[nt], 0.0f);
        rout[(size_t)row * 64 + nt * 16 + col] = v;
        scol[nt] += v; qcol[nt] += v * v;
      }
    }
  }

  // BN partials: quad-reduce then cross-wave via LDS
#pragma unroll
  for (int nt = 0; nt < 4; ++nt) {
    float s = scol[nt], q = qcol[nt];
    s += __shfl_xor(s, 16); s += __shfl_xor(s, 32);
    q += __shfl_xor(q, 16); q += __shfl_xor(q, 32);
    if (quad == 0) {
      red[wave * 128 + nt * 16 + col] = s;
      red[wave * 128 + 64 + nt * 16 + col] = q;
    }
  }
  __syncthreads();
  if (tid < 128)
    part[blockIdx.x * 128 + tid] =
        red[tid] + red[128 + tid] + red[256 + tid] + red[384 + tid];
}

// ---------------------------------------------------------------- BN finalize
__global__ __launch_bounds__(1024) void finalize(
    const float* __restrict__ part, const float* __restrict__ gma,
    const float* __restrict__ bta, float* __restrict__ ss) {
  __shared__ double sh[1024];
  __shared__ double tot[128];
  int tid = threadIdx.x;
  int col = tid & 127, chunk = tid >> 7;
  double a = 0.0;
  for (int b = chunk; b < NBLKM; b += 8) a += (double)part[b * 128 + col];
  sh[tid] = a;
  __syncthreads();
  if (tid < 128) {
    double v = 0.0;
#pragma unroll
    for (int k = 0; k < 8; ++k) v += sh[k * 128 + tid];
    tot[tid] = v;
  }
  __syncthreads();
  if (tid < 64) {
    double mean = tot[tid] / (double)NN;
    double var = tot[64 + tid] / (double)NN - mean * mean;
    double sc = (double)gma[tid] / sqrt(var + 1e-5);
    ss[tid] = (float)sc;
    ss[64 + tid] = (float)((double)bta[tid] - mean * sc);
  }
}

// ---------------------------------------------------------------- pool + fc
__global__ __launch_bounds__(64) void pool_fc(
    const float* __restrict__ r3, const float* __restrict__ ss,
    const float* __restrict__ wfc, const float* __restrict__ bfc,
    float* __restrict__ out) {
  int g = blockIdx.x, c = threadIdx.x;
  const float* base = r3 + (size_t)g * NPG * 64;
  float s = 0.f;
#pragma unroll
  for (int n = 0; n < NPG; ++n) s += base[n * 64 + c];
  float pooled = fmaf(ss[c], s, (float)NPG * ss[64 + c]);
#pragma unroll
  for (int j = 0; j < 3; ++j) {
    float v = pooled * wfc[c * 3 + j];
    for (int m = 32; m; m >>= 1) v += __shfl_xor(v, m);
    if (c == 0) out[g * 3 + j] = v + bfc[j];
  }
}

// ---------------------------------------------------------------- launch
extern "C" void kernel_launch(void* const* d_in, const int* in_sizes, int n_in,
                              void* d_out, int out_size, void* d_ws, size_t ws_size,
                              hipStream_t stream) {
  const float* x    = (const float*)d_in[0];
  const int*   srcE = (const int*)d_in[1];
  const int*   dstE = (const int*)d_in[2];
  const float* W1a = (const float*)d_in[4],  *b1a = (const float*)d_in[5];
  const float* W1b = (const float*)d_in[6],  *b1b = (const float*)d_in[7];
  const float* g1  = (const float*)d_in[8],  *be1 = (const float*)d_in[9];
  const float* W2a = (const float*)d_in[10], *b2a = (const float*)d_in[11];
  const float* W2b = (const float*)d_in[12], *b2b = (const float*)d_in[13];
  const float* g2  = (const float*)d_in[14], *be2 = (const float*)d_in[15];
  const float* W3a = (const float*)d_in[16], *b3a = (const float*)d_in[17];
  const float* W3b = (const float*)d_in[18], *b3b = (const float*)d_in[19];
  const float* g3  = (const float*)d_in[20], *be3 = (const float*)d_in[21];
  const float* Wfc = (const float*)d_in[22], *bfc = (const float*)d_in[23];

  float* ws = (float*)d_ws;
  float*    R     = ws + OFF_R;
  void*     AGGBF = (void*)(ws + OFF_AGGBF);
  int*      CSR   = (int*)(ws + OFF_CSR);
  int*      CNT   = (int*)(ws + OFF_CNT);
  int*      OFFA  = (int*)(ws + OFF_OFFA);
  int*      CUR   = (int*)(ws + OFF_CUR);
  int*      BSUM  = (int*)(ws + OFF_BSUM);
  int*      BSCAN = (int*)(ws + OFF_BSCAN);
  float*    PART  = ws + OFF_PART;
  float*    WT    = ws + OFF_WT;
  ushort_t* WTB   = (ushort_t*)(ws + OFF_WTB);
  float*    SS    = ws + OFF_SS;

  prep_weights<<<6, 256, 0, stream>>>(W1a, W1b, W2a, W2b, W3a, W3b, WT, WTB);

  // ---- CSR build
  hipMemsetAsync(CNT, 0, NN * sizeof(int), stream);
  hist<<<NE / 256, 256, 0, stream>>>(dstE, CNT);
  scanA<<<NBLK, 256, 0, stream>>>(CNT, OFFA, BSUM);
  scanB<<<1, 256, 0, stream>>>(BSUM, BSCAN);
  scanC<<<NBLK, 256, 0, stream>>>(OFFA, BSCAN, CUR);
  place<<<NE / 256, 256, 0, stream>>>(srcE, dstE, CUR, CSR);

  // ---- layer 1
  gather1<<<NN / 256, 256, 0, stream>>>((const float4*)x, CSR, OFFA, CNT,
                                        (float4*)AGGBF);
  mlp_mfma<true><<<NBLKM, 256, 0, stream>>>(AGGBF, nullptr, WT, b1a,
                                            WTB + WB_W1B, b1b, R, PART);
  finalize<<<1, 1024, 0, stream>>>(PART, g1, be1, SS + 0);

  // ---- layer 2
  gather64<<<NN / 4, 256, 0, stream>>>(R, CSR, OFFA, CNT, SS + 0,
                                       (__hip_bfloat16*)AGGBF);
  mlp_mfma<false><<<NBLKM, 256, 0, stream>>>(AGGBF, WTB + WB_W2A, nullptr, b2a,
                                             WTB + WB_W2B, b2b, R, PART);
  finalize<<<1, 1024, 0, stream>>>(PART, g2, be2, SS + 128);

  // ---- layer 3
  gather64<<<NN / 4, 256, 0, stream>>>(R, CSR, OFFA, CNT, SS + 128,
                                       (__hip_bfloat16*)AGGBF);
  mlp_mfma<false><<<NBLKM, 256, 0, stream>>>(AGGBF, WTB + WB_W3A, nullptr, b3a,
                                             WTB + WB_W3B, b3b, R, PART);
  finalize<<<1, 1024, 0, stream>>>(PART, g3, be3, SS + 256);

  // ---- pool + classifier
  pool_fc<<<NG, 64, 0, stream>>>(R, SS + 256, Wfc, bfc, (float*)d_out);
}

// Round 4
// 920.197 us; speedup vs baseline: 4.4566x; 1.4231x over previous
//
#include <hip/hip_runtime.h>
#include <hip/hip_bf16.h>

// Problem constants (fixed by the reference)
#define NN   507904          // nodes = 8192*62
#define NE   4063232         // edges = NN*8
#define NG   8192            // graphs
#define NPG  62              // nodes per graph
#define NBLKM 992            // NN/512 (mlp grid)

// Bucket sort parameters
#define NB    248            // buckets = NN/2048 (exact)
#define BRNG  2048           // nodes per bucket (power of 2: bucket = dst>>11)
#define BCAP  17152          // bucket capacity (mean 16384, +6 sigma)
#define P3BLK 992            // NE/4096 (exact)

// ---------------------------------------------------------------- ws layout (4B units)
#define OFF_R     0                          // NN*64 fp32 features
#define OFF_AGGBF (OFF_R + NN * 64)          // t: bf16 NN*64 | ALSO aliased: RECS (34MB, dead before gather1)
#define OFF_CSR   (OFF_AGGBF + NN * 32)      // NE ints
#define OFF_CNT   (OFF_CSR + NE)             // NN ints
#define OFF_OFFA  (OFF_CNT + NN)             // NN ints
#define OFF_BCUR  (OFF_OFFA + NN)            // 256 ints
#define OFF_BSTART (OFF_BCUR + 256)          // 256 ints
#define OFF_PART  (OFF_BSTART + 256)         // NBLKM*128 floats
#define OFF_WT    (OFF_PART + NBLKM * 128)   // fp32 W1a^T: 256 floats
#define OFF_WTB   (OFF_WT + 256)             // bf16 transposed weights: 20480 bf16
#define OFF_SS    (OFF_WTB + 10240)          // 3 x (scale[64], shift[64])
// total ~= 54.9M units ~= 220 MB

// bf16 weight offsets (ushort units)
#define WB_W1B 0
#define WB_W2A 4096
#define WB_W2B 8192
#define WB_W3A 12288
#define WB_W3B 16384

typedef __attribute__((ext_vector_type(8))) short short8;
typedef __attribute__((ext_vector_type(4))) float f32x4;
typedef unsigned short ushort_t;

__device__ __forceinline__ ushort_t f2bf_bits(float f) {
  union { float f; unsigned u; } x; x.f = f;
  unsigned r = x.u + 0x7FFF + ((x.u >> 16) & 1);
  return (ushort_t)(r >> 16);
}

// ---------------------------------------------------------------- weight prep
__global__ __launch_bounds__(256) void prep_weights(
    const float* __restrict__ w1a, const float* __restrict__ w1b,
    const float* __restrict__ w2a, const float* __restrict__ w2b,
    const float* __restrict__ w3a, const float* __restrict__ w3b,
    float* __restrict__ wt, ushort_t* __restrict__ wtb) {
  int b = blockIdx.x, tid = threadIdx.x;
  if (b == 0) {
    if (tid < 256) {
      int k = tid >> 6, n = tid & 63;          // src [4][64]
      wt[n * 4 + k] = w1a[tid];
    }
  } else {
    const float* s; ushort_t* d;
    switch (b) {
      case 1: s = w1b; d = wtb + WB_W1B; break;
      case 2: s = w2a; d = wtb + WB_W2A; break;
      case 3: s = w2b; d = wtb + WB_W2B; break;
      case 4: s = w3a; d = wtb + WB_W3A; break;
      default: s = w3b; d = wtb + WB_W3B; break;
    }
    for (int i = tid; i < 4096; i += 256) {
      int k = i >> 6, n = i & 63;              // src [k][n]
      d[n * 64 + k] = f2bf_bits(s[i]);         // dst [n][k]
    }
  }
}

// ---------------------------------------------------------------- CSR build: phase 1
// Bin edges into 248 buckets by dst>>11. LDS-staged so global writes are
// bucket-contiguous ~128B runs; one bulk atomic per (block,bucket).
__global__ __launch_bounds__(256) void p3_bin(
    const int* __restrict__ src, const int* __restrict__ dst,
    int* __restrict__ bcur, uint2* __restrict__ recs) {
  __shared__ int histo[256];     // counts, then exclusive scan values
  __shared__ int scan_s[256];
  __shared__ int base_s[256];    // global reserved base per bucket
  __shared__ int cur_s[256];     // local placement cursor
  __shared__ uint2 buf[4096];    // 32 KB reorder buffer
  const int tid = threadIdx.x;
  const int e0 = blockIdx.x * 4096;

  histo[tid] = 0;
  __syncthreads();

  int d_[16], s_[16];
#pragma unroll
  for (int k = 0; k < 16; ++k) {
    int e = e0 + k * 256 + tid;               // coalesced
    d_[k] = dst[e]; s_[k] = src[e];
    atomicAdd(&histo[d_[k] >> 11], 1);        // LDS atomic
  }
  __syncthreads();

  int v = histo[tid];
  scan_s[tid] = v; __syncthreads();
  for (int s = 1; s < 256; s <<= 1) {
    int add = (tid >= s) ? scan_s[tid - s] : 0;
    __syncthreads();
    scan_s[tid] += add;
    __syncthreads();
  }
  int excl = scan_s[tid] - v;
  if (tid < NB) base_s[tid] = atomicAdd(&bcur[tid], v);   // bulk reserve
  cur_s[tid] = excl;
  histo[tid] = excl;                           // keep exclusive scan
  __syncthreads();

  // bucket-ordered placement in LDS
#pragma unroll
  for (int k = 0; k < 16; ++k) {
    int b = d_[k] >> 11;
    int p = atomicAdd(&cur_s[b], 1);
    uint2 r; r.x = (unsigned)d_[k]; r.y = (unsigned)s_[k];
    buf[p] = r;
  }
  __syncthreads();

  // write out: entry i of bucket b -> recs[b*BCAP + base_s[b] + (i - excl[b])]
  for (int i = tid; i < 4096; i += 256) {
    uint2 r = buf[i];
    int b = (int)(r.x >> 11);
    int g = base_s[b] + (i - histo[b]);
    if (g < BCAP) recs[(size_t)b * BCAP + g] = r;   // overflow guard (never fires)
  }
}

// ---------------------------------------------------------------- CSR build: phase 2
__global__ __launch_bounds__(256) void p_scan248(const int* __restrict__ bcur,
                                                 int* __restrict__ bstart) {
  __shared__ int sh[256];
  int tid = threadIdx.x;
  int v = (tid < NB) ? bcur[tid] : 0;
  sh[tid] = v; __syncthreads();
  for (int s = 1; s < 256; s <<= 1) {
    int add = (tid >= s) ? sh[tid - s] : 0;
    __syncthreads();
    sh[tid] += add;
    __syncthreads();
  }
  if (tid < NB) bstart[tid] = sh[tid] - v;
}

// ---------------------------------------------------------------- CSR build: phase 3
// One workgroup per bucket: LDS histogram over 2048 local nodes, LDS scan,
// emit cnt/offa coalesced, place csr within an L2-resident 64KB window.
__global__ __launch_bounds__(1024) void p4_build(
    const uint2* __restrict__ recs, const int* __restrict__ bcur,
    const int* __restrict__ bstart, int* __restrict__ csr,
    int* __restrict__ cnt, int* __restrict__ offa) {
  __shared__ int lcnt[2048];
  __shared__ int pscan[1024];
  __shared__ int sexc[2048];      // exclusive scan, then reused as cursors
  const int b = blockIdx.x, tid = threadIdx.x;
  int m = bcur[b]; if (m > BCAP) m = BCAP;
  const int cbase = bstart[b];
  const int nbase = b << 11;
  const uint2* rp = recs + (size_t)b * BCAP;

  lcnt[tid] = 0; lcnt[1024 + tid] = 0;
  __syncthreads();
  for (int i = tid; i < m; i += 1024)
    atomicAdd(&lcnt[rp[i].x & (BRNG - 1)], 1);
  __syncthreads();

  // exclusive scan over 2048 (2 elems/thread)
  int a0 = lcnt[2 * tid], a1 = lcnt[2 * tid + 1];
  int ps = a0 + a1;
  pscan[tid] = ps; __syncthreads();
  for (int s = 1; s < 1024; s <<= 1) {
    int add = (tid >= s) ? pscan[tid - s] : 0;
    __syncthreads();
    pscan[tid] += add;
    __syncthreads();
  }
  int e0 = pscan[tid] - ps;
  sexc[2 * tid] = e0; sexc[2 * tid + 1] = e0 + a0;
  __syncthreads();

  // emit global cnt/offa (coalesced)
  cnt[nbase + tid] = lcnt[tid];
  cnt[nbase + 1024 + tid] = lcnt[1024 + tid];
  offa[nbase + tid] = cbase + sexc[tid];
  offa[nbase + 1024 + tid] = cbase + sexc[1024 + tid];
  __syncthreads();

  // place (sexc now serves as cursors)
  for (int i = tid; i < m; i += 1024) {
    uint2 r = rp[i];
    int p = atomicAdd(&sexc[r.x & (BRNG - 1)], 1);
    csr[cbase + p] = (int)r.y;
  }
}

// ---------------------------------------------------------------- gather L1 (C=4)
__global__ __launch_bounds__(256) void gather1(
    const float4* __restrict__ x, const int* __restrict__ csr,
    const int* __restrict__ offa, const int* __restrict__ cnt,
    float4* __restrict__ tout) {
  int n = blockIdx.x * 256 + threadIdx.x;
  float4 a = x[n];
  int off = offa[n], deg = cnt[n];
  const int* cp = csr + off;
  int j = 0;
  for (; j + 4 <= deg; j += 4) {
    int s0 = cp[j], s1 = cp[j + 1], s2 = cp[j + 2], s3 = cp[j + 3];
    float4 v0 = x[s0], v1 = x[s1], v2 = x[s2], v3 = x[s3];
    a.x += v0.x + v1.x + v2.x + v3.x;
    a.y += v0.y + v1.y + v2.y + v3.y;
    a.z += v0.z + v1.z + v2.z + v3.z;
    a.w += v0.w + v1.w + v2.w + v3.w;
  }
  for (; j < deg; ++j) {
    float4 v = x[cp[j]];
    a.x += v.x; a.y += v.y; a.z += v.z; a.w += v.w;
  }
  tout[n] = a;
}

// ---------------------------------------------------------------- gather L2/3 (C=64)
__global__ __launch_bounds__(256) void gather64(
    const float* __restrict__ h, const int* __restrict__ csr,
    const int* __restrict__ offa, const int* __restrict__ cnt,
    const float* __restrict__ ss, __hip_bfloat16* __restrict__ tout) {
  const int c = threadIdx.x & 63;
  const int n = blockIdx.x * 4 + (threadIdx.x >> 6);
  const float sc = ss[c], sf = ss[64 + c];
  float acc = fmaf(sc, h[(size_t)n * 64 + c], sf);
  const int off = offa[n], deg = cnt[n];
  const int* cp = csr + off;
  int j = 0;
  for (; j + 4 <= deg; j += 4) {
    int s0 = cp[j], s1 = cp[j + 1], s2 = cp[j + 2], s3 = cp[j + 3];
    float v0 = h[(size_t)s0 * 64 + c];
    float v1 = h[(size_t)s1 * 64 + c];
    float v2 = h[(size_t)s2 * 64 + c];
    float v3 = h[(size_t)s3 * 64 + c];
    acc += fmaf(sc, v0, sf) + fmaf(sc, v1, sf) + fmaf(sc, v2, sf) + fmaf(sc, v3, sf);
  }
  for (; j < deg; ++j)
    acc += fmaf(sc, h[(size_t)cp[j] * 64 + c], sf);
  tout[(size_t)n * 64 + c] = __float2bfloat16(acc);
}

// ---------------------------------------------------------------- MFMA MLP
// 4 waves/block, 16 rows/wave, 8 iters -> 512 nodes/block. grid = 992.
template <bool L1>
__global__ __launch_bounds__(256) void mlp_mfma(
    const void* __restrict__ tin,
    const ushort_t* __restrict__ WaTb,   // bf16 [n][k] (unused if L1)
    const float* __restrict__ WaTf,      // fp32 [o][c] (L1 only)
    const float* __restrict__ ba,
    const ushort_t* __restrict__ WbTb,   // bf16 [n][k]
    const float* __restrict__ bb,
    float* __restrict__ rout, float* __restrict__ part) {
  __shared__ __align__(16) ushort_t zt[4096];   // 4 waves x 16x64 bf16, XOR-swizzled
  __shared__ float red[512];
  __shared__ float wa_l1[320];
  const int tid = threadIdx.x;
  const int wave = tid >> 6, lane = tid & 63;
  const int col = lane & 15, quad = lane >> 4;

  if (L1) {
    if (tid < 256) wa_l1[tid] = WaTf[tid];
    if (tid < 64) wa_l1[256 + tid] = ba[tid];
    __syncthreads();
  }

  short8 bWa[2][4], bWb[2][4];
#pragma unroll
  for (int k0 = 0; k0 < 2; ++k0)
#pragma unroll
    for (int nt = 0; nt < 4; ++nt) {
      if (!L1) bWa[k0][nt] = *(const short8*)(WaTb + (nt * 16 + col) * 64 + k0 * 32 + quad * 8);
      bWb[k0][nt] = *(const short8*)(WbTb + (nt * 16 + col) * 64 + k0 * 32 + quad * 8);
    }
  float ba_n[4], bb_n[4];
#pragma unroll
  for (int nt = 0; nt < 4; ++nt) {
    if (!L1) ba_n[nt] = ba[nt * 16 + col];
    bb_n[nt] = bb[nt * 16 + col];
  }

  const int wbase = wave * 1024;
  float scol[4] = {0, 0, 0, 0}, qcol[4] = {0, 0, 0, 0};

  for (int it = 0; it < 8; ++it) {
    const int tile = blockIdx.x * 512 + it * 64 + wave * 16;
    short8 az0, az1;

    if constexpr (L1) {
      float4 t4 = ((const float4*)tin)[tile + col];
#pragma unroll
      for (int k0 = 0; k0 < 2; ++k0) {
        short8 az;
#pragma unroll
        for (int j = 0; j < 8; ++j) {
          int o = k0 * 32 + quad * 8 + j;
          float z = wa_l1[256 + o];
          z = fmaf(t4.x, wa_l1[o * 4 + 0], z);
          z = fmaf(t4.y, wa_l1[o * 4 + 1], z);
          z = fmaf(t4.z, wa_l1[o * 4 + 2], z);
          z = fmaf(t4.w, wa_l1[o * 4 + 3], z);
          az[j] = (short)f2bf_bits(fmaxf(z, 0.0f));
        }
        if (k0 == 0) az0 = az; else az1 = az;
      }
    } else {
      const ushort_t* tb = (const ushort_t*)tin;
      short8 a0 = *(const short8*)(tb + (size_t)(tile + col) * 64 + quad * 8);
      short8 a1 = *(const short8*)(tb + (size_t)(tile + col) * 64 + 32 + quad * 8);
      f32x4 acc1[4];
#pragma unroll
      for (int nt = 0; nt < 4; ++nt) acc1[nt] = (f32x4){0.f, 0.f, 0.f, 0.f};
#pragma unroll
      for (int nt = 0; nt < 4; ++nt) {
        acc1[nt] = __builtin_amdgcn_mfma_f32_16x16x32_bf16(a0, bWa[0][nt], acc1[nt], 0, 0, 0);
        acc1[nt] = __builtin_amdgcn_mfma_f32_16x16x32_bf16(a1, bWa[1][nt], acc1[nt], 0, 0, 0);
      }
#pragma unroll
      for (int nt = 0; nt < 4; ++nt) {
        int oblk = nt * 2 + (col >> 3);
#pragma unroll
        for (int r = 0; r < 4; ++r) {
          int row = quad * 4 + r;
          float z = fmaxf(acc1[nt][r] + ba_n[nt], 0.0f);
          zt[wbase + row * 64 + (((oblk ^ (row & 7)) << 3) | (col & 7))] = f2bf_bits(z);
        }
      }
      int m = col;
      az0 = *(const short8*)&zt[wbase + m * 64 + ((quad ^ (m & 7)) << 3)];
      az1 = *(const short8*)&zt[wbase + m * 64 + (((4 + quad) ^ (m & 7)) << 3)];
    }

    f32x4 acc2[4];
#pragma unroll
    for (int nt = 0; nt < 4; ++nt) acc2[nt] = (f32x4){0.f, 0.f, 0.f, 0.f};
#pragma unroll
    for (int nt = 0; nt < 4; ++nt) {
      acc2[nt] = __builtin_amdgcn_mfma_f32_16x16x32_bf16(az0, bWb[0][nt], acc2[nt], 0, 0, 0);
      acc2[nt] = __builtin_amdgcn_mfma_f32_16x16x32_bf16(az1, bWb[1][nt], acc2[nt], 0, 0, 0);
    }
#pragma unroll
    for (int nt = 0; nt < 4; ++nt) {
#pragma unroll
      for (int r = 0; r < 4; ++r) {
        int row = tile + quad * 4 + r;
        float v = fmaxf(acc2[nt][r] + bb_n[nt], 0.0f);
        rout[(size_t)row * 64 + nt * 16 + col] = v;
        scol[nt] += v; qcol[nt] += v * v;
      }
    }
  }

#pragma unroll
  for (int nt = 0; nt < 4; ++nt) {
    float s = scol[nt], q = qcol[nt];
    s += __shfl_xor(s, 16); s += __shfl_xor(s, 32);
    q += __shfl_xor(q, 16); q += __shfl_xor(q, 32);
    if (quad == 0) {
      red[wave * 128 + nt * 16 + col] = s;
      red[wave * 128 + 64 + nt * 16 + col] = q;
    }
  }
  __syncthreads();
  if (tid < 128)
    part[blockIdx.x * 128 + tid] =
        red[tid] + red[128 + tid] + red[256 + tid] + red[384 + tid];
}

// ---------------------------------------------------------------- BN finalize
__global__ __launch_bounds__(1024) void finalize(
    const float* __restrict__ part, const float* __restrict__ gma,
    const float* __restrict__ bta, float* __restrict__ ss) {
  __shared__ double sh[1024];
  __shared__ double tot[128];
  int tid = threadIdx.x;
  int col = tid & 127, chunk = tid >> 7;
  double a = 0.0;
  for (int b = chunk; b < NBLKM; b += 8) a += (double)part[b * 128 + col];
  sh[tid] = a;
  __syncthreads();
  if (tid < 128) {
    double v = 0.0;
#pragma unroll
    for (int k = 0; k < 8; ++k) v += sh[k * 128 + tid];
    tot[tid] = v;
  }
  __syncthreads();
  if (tid < 64) {
    double mean = tot[tid] / (double)NN;
    double var = tot[64 + tid] / (double)NN - mean * mean;
    double sc = (double)gma[tid] / sqrt(var + 1e-5);
    ss[tid] = (float)sc;
    ss[64 + tid] = (float)((double)bta[tid] - mean * sc);
  }
}

// ---------------------------------------------------------------- pool + fc
__global__ __launch_bounds__(64) void pool_fc(
    const float* __restrict__ r3, const float* __restrict__ ss,
    const float* __restrict__ wfc, const float* __restrict__ bfc,
    float* __restrict__ out) {
  int g = blockIdx.x, c = threadIdx.x;
  const float* base = r3 + (size_t)g * NPG * 64;
  float s = 0.f;
#pragma unroll
  for (int n = 0; n < NPG; ++n) s += base[n * 64 + c];
  float pooled = fmaf(ss[c], s, (float)NPG * ss[64 + c]);
#pragma unroll
  for (int j = 0; j < 3; ++j) {
    float v = pooled * wfc[c * 3 + j];
    for (int m = 32; m; m >>= 1) v += __shfl_xor(v, m);
    if (c == 0) out[g * 3 + j] = v + bfc[j];
  }
}

// ---------------------------------------------------------------- launch
extern "C" void kernel_launch(void* const* d_in, const int* in_sizes, int n_in,
                              void* d_out, int out_size, void* d_ws, size_t ws_size,
                              hipStream_t stream) {
  const float* x    = (const float*)d_in[0];
  const int*   srcE = (const int*)d_in[1];
  const int*   dstE = (const int*)d_in[2];
  const float* W1a = (const float*)d_in[4],  *b1a = (const float*)d_in[5];
  const float* W1b = (const float*)d_in[6],  *b1b = (const float*)d_in[7];
  const float* g1  = (const float*)d_in[8],  *be1 = (const float*)d_in[9];
  const float* W2a = (const float*)d_in[10], *b2a = (const float*)d_in[11];
  const float* W2b = (const float*)d_in[12], *b2b = (const float*)d_in[13];
  const float* g2  = (const float*)d_in[14], *be2 = (const float*)d_in[15];
  const float* W3a = (const float*)d_in[16], *b3a = (const float*)d_in[17];
  const float* W3b = (const float*)d_in[18], *b3b = (const float*)d_in[19];
  const float* g3  = (const float*)d_in[20], *be3 = (const float*)d_in[21];
  const float* Wfc = (const float*)d_in[22], *bfc = (const float*)d_in[23];

  float* ws = (float*)d_ws;
  float*    R      = ws + OFF_R;
  void*     AGGBF  = (void*)(ws + OFF_AGGBF);
  uint2*    RECS   = (uint2*)(ws + OFF_AGGBF);   // alias: dead before gather1
  int*      CSR    = (int*)(ws + OFF_CSR);
  int*      CNT    = (int*)(ws + OFF_CNT);
  int*      OFFA   = (int*)(ws + OFF_OFFA);
  int*      BCUR   = (int*)(ws + OFF_BCUR);
  int*      BSTART = (int*)(ws + OFF_BSTART);
  float*    PART   = ws + OFF_PART;
  float*    WT     = ws + OFF_WT;
  ushort_t* WTB    = (ushort_t*)(ws + OFF_WTB);
  float*    SS     = ws + OFF_SS;

  prep_weights<<<6, 256, 0, stream>>>(W1a, W1b, W2a, W2b, W3a, W3b, WT, WTB);

  // ---- CSR build (bucket sort, atomic-light)
  hipMemsetAsync(BCUR, 0, 256 * sizeof(int), stream);
  p3_bin<<<P3BLK, 256, 0, stream>>>(srcE, dstE, BCUR, RECS);
  p_scan248<<<1, 256, 0, stream>>>(BCUR, BSTART);
  p4_build<<<NB, 1024, 0, stream>>>(RECS, BCUR, BSTART, CSR, CNT, OFFA);

  // ---- layer 1
  gather1<<<NN / 256, 256, 0, stream>>>((const float4*)x, CSR, OFFA, CNT,
                                        (float4*)AGGBF);
  mlp_mfma<true><<<NBLKM, 256, 0, stream>>>(AGGBF, nullptr, WT, b1a,
                                            WTB + WB_W1B, b1b, R, PART);
  finalize<<<1, 1024, 0, stream>>>(PART, g1, be1, SS + 0);

  // ---- layer 2
  gather64<<<NN / 4, 256, 0, stream>>>(R, CSR, OFFA, CNT, SS + 0,
                                       (__hip_bfloat16*)AGGBF);
  mlp_mfma<false><<<NBLKM, 256, 0, stream>>>(AGGBF, WTB + WB_W2A, nullptr, b2a,
                                             WTB + WB_W2B, b2b, R, PART);
  finalize<<<1, 1024, 0, stream>>>(PART, g2, be2, SS + 128);

  // ---- layer 3
  gather64<<<NN / 4, 256, 0, stream>>>(R, CSR, OFFA, CNT, SS + 128,
                                       (__hip_bfloat16*)AGGBF);
  mlp_mfma<false><<<NBLKM, 256, 0, stream>>>(AGGBF, WTB + WB_W3A, nullptr, b3a,
                                             WTB + WB_W3B, b3b, R, PART);
  finalize<<<1, 1024, 0, stream>>>(PART, g3, be3, SS + 256);

  // ---- pool + classifier
  pool_fc<<<NG, 64, 0, stream>>>(R, SS + 256, Wfc, bfc, (float*)d_out);
}

// Round 5
// 884.597 us; speedup vs baseline: 4.6360x; 1.0402x over previous
//
#include <hip/hip_runtime.h>
#include <hip/hip_bf16.h>

// Problem constants (fixed by the reference)
#define NN   507904          // nodes = 8192*62
#define NE   4063232         // edges = NN*8
#define NG   8192            // graphs
#define NPG  62              // nodes per graph
#define NBLKM 992            // NN/512 (mlp grid)

// Bucket sort parameters
#define NB    248            // buckets = NN/2048 (exact)
#define BRNG  2048           // nodes per bucket (bucket = dst>>11)
#define BCAP  17152          // bucket capacity (mean 16384, +6 sigma)
#define P3BLK 992            // NE/4096 (exact)

// ---------------------------------------------------------------- ws layout (4B units)
// R region holds: bf16 features (layers 1/2 output, NN*32 units) and, after
// the layer-3 gather consumed them, fp32 layer-3 output (NN*64 units).
#define OFF_R     0                          // NN*64 units
#define OFF_AGGBF (OFF_R + NN * 64)          // t: bf16 NN*64 | aliased: RECS (34MB)
#define OFF_CSR   (OFF_AGGBF + NN * 32)      // NE ints
#define OFF_CNT   (OFF_CSR + NE)             // NN ints
#define OFF_OFFA  (OFF_CNT + NN)             // NN ints
#define OFF_BCUR  (OFF_OFFA + NN)            // 256 ints
#define OFF_BSTART (OFF_BCUR + 256)          // 256 ints
#define OFF_PART  (OFF_BSTART + 256)         // NBLKM*128 floats
#define OFF_WT    (OFF_PART + NBLKM * 128)   // fp32 W1a^T: 256 floats
#define OFF_WTB   (OFF_WT + 256)             // bf16 transposed weights
#define OFF_SS    (OFF_WTB + 10240)          // 3 x (scale[64], shift[64])

// bf16 weight offsets (ushort units)
#define WB_W1B 0
#define WB_W2A 4096
#define WB_W2B 8192
#define WB_W3A 12288
#define WB_W3B 16384

typedef __attribute__((ext_vector_type(8))) short short8;
typedef __attribute__((ext_vector_type(4))) float f32x4;
typedef unsigned short ushort_t;

__device__ __forceinline__ ushort_t f2bf_bits(float f) {
  union { float f; unsigned u; } x; x.f = f;
  unsigned r = x.u + 0x7FFF + ((x.u >> 16) & 1);
  return (ushort_t)(r >> 16);
}
__device__ __forceinline__ float bf2f1(ushort_t u) {
  union { unsigned i; float f; } x; x.i = ((unsigned)u) << 16;
  return x.f;
}

// ---------------------------------------------------------------- weight prep
__global__ __launch_bounds__(256) void prep_weights(
    const float* __restrict__ w1a, const float* __restrict__ w1b,
    const float* __restrict__ w2a, const float* __restrict__ w2b,
    const float* __restrict__ w3a, const float* __restrict__ w3b,
    float* __restrict__ wt, ushort_t* __restrict__ wtb) {
  int b = blockIdx.x, tid = threadIdx.x;
  if (b == 0) {
    if (tid < 256) {
      int k = tid >> 6, n = tid & 63;          // src [4][64]
      wt[n * 4 + k] = w1a[tid];
    }
  } else {
    const float* s; ushort_t* d;
    switch (b) {
      case 1: s = w1b; d = wtb + WB_W1B; break;
      case 2: s = w2a; d = wtb + WB_W2A; break;
      case 3: s = w2b; d = wtb + WB_W2B; break;
      case 4: s = w3a; d = wtb + WB_W3A; break;
      default: s = w3b; d = wtb + WB_W3B; break;
    }
    for (int i = tid; i < 4096; i += 256) {
      int k = i >> 6, n = i & 63;              // src [k][n]
      d[n * 64 + k] = f2bf_bits(s[i]);         // dst [n][k]
    }
  }
}

// ---------------------------------------------------------------- CSR build: phase 1
__global__ __launch_bounds__(256) void p3_bin(
    const int* __restrict__ src, const int* __restrict__ dst,
    int* __restrict__ bcur, uint2* __restrict__ recs) {
  __shared__ int histo[256];
  __shared__ int scan_s[256];
  __shared__ int base_s[256];
  __shared__ int cur_s[256];
  __shared__ uint2 buf[4096];
  const int tid = threadIdx.x;
  const int e0 = blockIdx.x * 4096;

  histo[tid] = 0;
  __syncthreads();

  int d_[16], s_[16];
#pragma unroll
  for (int k = 0; k < 16; ++k) {
    int e = e0 + k * 256 + tid;
    d_[k] = dst[e]; s_[k] = src[e];
    atomicAdd(&histo[d_[k] >> 11], 1);
  }
  __syncthreads();

  int v = histo[tid];
  scan_s[tid] = v; __syncthreads();
  for (int s = 1; s < 256; s <<= 1) {
    int add = (tid >= s) ? scan_s[tid - s] : 0;
    __syncthreads();
    scan_s[tid] += add;
    __syncthreads();
  }
  int excl = scan_s[tid] - v;
  if (tid < NB) base_s[tid] = atomicAdd(&bcur[tid], v);
  cur_s[tid] = excl;
  histo[tid] = excl;
  __syncthreads();

#pragma unroll
  for (int k = 0; k < 16; ++k) {
    int b = d_[k] >> 11;
    int p = atomicAdd(&cur_s[b], 1);
    uint2 r; r.x = (unsigned)d_[k]; r.y = (unsigned)s_[k];
    buf[p] = r;
  }
  __syncthreads();

  for (int i = tid; i < 4096; i += 256) {
    uint2 r = buf[i];
    int b = (int)(r.x >> 11);
    int g = base_s[b] + (i - histo[b]);
    if (g < BCAP) recs[(size_t)b * BCAP + g] = r;
  }
}

// ---------------------------------------------------------------- CSR build: phase 2
__global__ __launch_bounds__(256) void p_scan248(const int* __restrict__ bcur,
                                                 int* __restrict__ bstart) {
  __shared__ int sh[256];
  int tid = threadIdx.x;
  int v = (tid < NB) ? bcur[tid] : 0;
  sh[tid] = v; __syncthreads();
  for (int s = 1; s < 256; s <<= 1) {
    int add = (tid >= s) ? sh[tid - s] : 0;
    __syncthreads();
    sh[tid] += add;
    __syncthreads();
  }
  if (tid < NB) bstart[tid] = sh[tid] - v;
}

// ---------------------------------------------------------------- CSR build: phase 3
__global__ __launch_bounds__(1024) void p4_build(
    const uint2* __restrict__ recs, const int* __restrict__ bcur,
    const int* __restrict__ bstart, int* __restrict__ csr,
    int* __restrict__ cnt, int* __restrict__ offa) {
  __shared__ int lcnt[2048];
  __shared__ int pscan[1024];
  __shared__ int sexc[2048];
  const int b = blockIdx.x, tid = threadIdx.x;
  int m = bcur[b]; if (m > BCAP) m = BCAP;
  const int cbase = bstart[b];
  const int nbase = b << 11;
  const uint2* rp = recs + (size_t)b * BCAP;

  lcnt[tid] = 0; lcnt[1024 + tid] = 0;
  __syncthreads();
  for (int i = tid; i < m; i += 1024)
    atomicAdd(&lcnt[rp[i].x & (BRNG - 1)], 1);
  __syncthreads();

  int a0 = lcnt[2 * tid], a1 = lcnt[2 * tid + 1];
  int ps = a0 + a1;
  pscan[tid] = ps; __syncthreads();
  for (int s = 1; s < 1024; s <<= 1) {
    int add = (tid >= s) ? pscan[tid - s] : 0;
    __syncthreads();
    pscan[tid] += add;
    __syncthreads();
  }
  int e0 = pscan[tid] - ps;
  sexc[2 * tid] = e0; sexc[2 * tid + 1] = e0 + a0;
  __syncthreads();

  cnt[nbase + tid] = lcnt[tid];
  cnt[nbase + 1024 + tid] = lcnt[1024 + tid];
  offa[nbase + tid] = cbase + sexc[tid];
  offa[nbase + 1024 + tid] = cbase + sexc[1024 + tid];
  __syncthreads();

  for (int i = tid; i < m; i += 1024) {
    uint2 r = rp[i];
    int p = atomicAdd(&sexc[r.x & (BRNG - 1)], 1);
    csr[cbase + p] = (int)r.y;
  }
}

// ---------------------------------------------------------------- gather L1 (C=4)
__global__ __launch_bounds__(256) void gather1(
    const float4* __restrict__ x, const int* __restrict__ csr,
    const int* __restrict__ offa, const int* __restrict__ cnt,
    float4* __restrict__ tout) {
  int n = blockIdx.x * 256 + threadIdx.x;
  float4 a = x[n];
  int off = offa[n], deg = cnt[n];
  const int* cp = csr + off;
  int j = 0;
  for (; j + 4 <= deg; j += 4) {
    int s0 = cp[j], s1 = cp[j + 1], s2 = cp[j + 2], s3 = cp[j + 3];
    float4 v0 = x[s0], v1 = x[s1], v2 = x[s2], v3 = x[s3];
    a.x += v0.x + v1.x + v2.x + v3.x;
    a.y += v0.y + v1.y + v2.y + v3.y;
    a.z += v0.z + v1.z + v2.z + v3.z;
    a.w += v0.w + v1.w + v2.w + v3.w;
  }
  for (; j < deg; ++j) {
    float4 v = x[cp[j]];
    a.x += v.x; a.y += v.y; a.z += v.z; a.w += v.w;
  }
  tout[n] = a;
}

// ---------------------------------------------------------------- gather L2/3 (C=64, bf16 rows)
__global__ __launch_bounds__(256) void gather64(
    const ushort_t* __restrict__ h, const int* __restrict__ csr,
    const int* __restrict__ offa, const int* __restrict__ cnt,
    const float* __restrict__ ss, ushort_t* __restrict__ tout) {
  const int c = threadIdx.x & 63;
  const int n = blockIdx.x * 4 + (threadIdx.x >> 6);
  const float sc = ss[c], sf = ss[64 + c];
  float acc = fmaf(sc, bf2f1(h[(size_t)n * 64 + c]), sf);
  const int off = offa[n], deg = cnt[n];
  const int* cp = csr + off;
  int j = 0;
  for (; j + 4 <= deg; j += 4) {
    int s0 = cp[j], s1 = cp[j + 1], s2 = cp[j + 2], s3 = cp[j + 3];
    float v0 = bf2f1(h[(size_t)s0 * 64 + c]);
    float v1 = bf2f1(h[(size_t)s1 * 64 + c]);
    float v2 = bf2f1(h[(size_t)s2 * 64 + c]);
    float v3 = bf2f1(h[(size_t)s3 * 64 + c]);
    acc += fmaf(sc, v0, sf) + fmaf(sc, v1, sf) + fmaf(sc, v2, sf) + fmaf(sc, v3, sf);
  }
  for (; j < deg; ++j)
    acc += fmaf(sc, bf2f1(h[(size_t)cp[j] * 64 + c]), sf);
  tout[(size_t)n * 64 + c] = f2bf_bits(acc);
}

// ---------------------------------------------------------------- MFMA MLP
// 4 waves/block, 16 rows/wave, 8 iters -> 512 nodes/block. grid = 992.
// BFOUT: write bf16 feature rows (layers 1/2); else fp32 (layer 3).
template <bool L1, bool BFOUT>
__global__ __launch_bounds__(256) void mlp_mfma(
    const void* __restrict__ tin,
    const ushort_t* __restrict__ WaTb,
    const float* __restrict__ WaTf,
    const float* __restrict__ ba,
    const ushort_t* __restrict__ WbTb,
    const float* __restrict__ bb,
    float* __restrict__ routf, ushort_t* __restrict__ routb,
    float* __restrict__ part) {
  __shared__ __align__(16) ushort_t zt[4096];
  __shared__ float red[512];
  __shared__ float wa_l1[320];
  const int tid = threadIdx.x;
  const int wave = tid >> 6, lane = tid & 63;
  const int col = lane & 15, quad = lane >> 4;

  if (L1) {
    if (tid < 256) wa_l1[tid] = WaTf[tid];
    if (tid < 64) wa_l1[256 + tid] = ba[tid];
    __syncthreads();
  }

  short8 bWa[2][4], bWb[2][4];
#pragma unroll
  for (int k0 = 0; k0 < 2; ++k0)
#pragma unroll
    for (int nt = 0; nt < 4; ++nt) {
      if (!L1) bWa[k0][nt] = *(const short8*)(WaTb + (nt * 16 + col) * 64 + k0 * 32 + quad * 8);
      bWb[k0][nt] = *(const short8*)(WbTb + (nt * 16 + col) * 64 + k0 * 32 + quad * 8);
    }
  float ba_n[4], bb_n[4];
#pragma unroll
  for (int nt = 0; nt < 4; ++nt) {
    if (!L1) ba_n[nt] = ba[nt * 16 + col];
    bb_n[nt] = bb[nt * 16 + col];
  }

  const int wbase = wave * 1024;
  float scol[4] = {0, 0, 0, 0}, qcol[4] = {0, 0, 0, 0};

  for (int it = 0; it < 8; ++it) {
    const int tile = blockIdx.x * 512 + it * 64 + wave * 16;
    short8 az0, az1;

    if constexpr (L1) {
      float4 t4 = ((const float4*)tin)[tile + col];
#pragma unroll
      for (int k0 = 0; k0 < 2; ++k0) {
        short8 az;
#pragma unroll
        for (int j = 0; j < 8; ++j) {
          int o = k0 * 32 + quad * 8 + j;
          float z = wa_l1[256 + o];
          z = fmaf(t4.x, wa_l1[o * 4 + 0], z);
          z = fmaf(t4.y, wa_l1[o * 4 + 1], z);
          z = fmaf(t4.z, wa_l1[o * 4 + 2], z);
          z = fmaf(t4.w, wa_l1[o * 4 + 3], z);
          az[j] = (short)f2bf_bits(fmaxf(z, 0.0f));
        }
        if (k0 == 0) az0 = az; else az1 = az;
      }
    } else {
      const ushort_t* tb = (const ushort_t*)tin;
      short8 a0 = *(const short8*)(tb + (size_t)(tile + col) * 64 + quad * 8);
      short8 a1 = *(const short8*)(tb + (size_t)(tile + col) * 64 + 32 + quad * 8);
      f32x4 acc1[4];
#pragma unroll
      for (int nt = 0; nt < 4; ++nt) acc1[nt] = (f32x4){0.f, 0.f, 0.f, 0.f};
#pragma unroll
      for (int nt = 0; nt < 4; ++nt) {
        acc1[nt] = __builtin_amdgcn_mfma_f32_16x16x32_bf16(a0, bWa[0][nt], acc1[nt], 0, 0, 0);
        acc1[nt] = __builtin_amdgcn_mfma_f32_16x16x32_bf16(a1, bWa[1][nt], acc1[nt], 0, 0, 0);
      }
#pragma unroll
      for (int nt = 0; nt < 4; ++nt) {
        int oblk = nt * 2 + (col >> 3);
#pragma unroll
        for (int r = 0; r < 4; ++r) {
          int row = quad * 4 + r;
          float z = fmaxf(acc1[nt][r] + ba_n[nt], 0.0f);
          zt[wbase + row * 64 + (((oblk ^ (row & 7)) << 3) | (col & 7))] = f2bf_bits(z);
        }
      }
      int m = col;
      az0 = *(const short8*)&zt[wbase + m * 64 + ((quad ^ (m & 7)) << 3)];
      az1 = *(const short8*)&zt[wbase + m * 64 + (((4 + quad) ^ (m & 7)) << 3)];
    }

    f32x4 acc2[4];
#pragma unroll
    for (int nt = 0; nt < 4; ++nt) acc2[nt] = (f32x4){0.f, 0.f, 0.f, 0.f};
#pragma unroll
    for (int nt = 0; nt < 4; ++nt) {
      acc2[nt] = __builtin_amdgcn_mfma_f32_16x16x32_bf16(az0, bWb[0][nt], acc2[nt], 0, 0, 0);
      acc2[nt] = __builtin_amdgcn_mfma_f32_16x16x32_bf16(az1, bWb[1][nt], acc2[nt], 0, 0, 0);
    }
#pragma unroll
    for (int nt = 0; nt < 4; ++nt) {
#pragma unroll
      for (int r = 0; r < 4; ++r) {
        int row = tile + quad * 4 + r;
        float v = fmaxf(acc2[nt][r] + bb_n[nt], 0.0f);
        if (BFOUT) routb[(size_t)row * 64 + nt * 16 + col] = f2bf_bits(v);
        else       routf[(size_t)row * 64 + nt * 16 + col] = v;
        scol[nt] += v; qcol[nt] += v * v;
      }
    }
  }

#pragma unroll
  for (int nt = 0; nt < 4; ++nt) {
    float s = scol[nt], q = qcol[nt];
    s += __shfl_xor(s, 16); s += __shfl_xor(s, 32);
    q += __shfl_xor(q, 16); q += __shfl_xor(q, 32);
    if (quad == 0) {
      red[wave * 128 + nt * 16 + col] = s;
      red[wave * 128 + 64 + nt * 16 + col] = q;
    }
  }
  __syncthreads();
  if (tid < 128)
    part[blockIdx.x * 128 + tid] =
        red[tid] + red[128 + tid] + red[256 + tid] + red[384 + tid];
}

// ---------------------------------------------------------------- BN finalize
__global__ __launch_bounds__(1024) void finalize(
    const float* __restrict__ part, const float* __restrict__ gma,
    const float* __restrict__ bta, float* __restrict__ ss) {
  __shared__ double sh[1024];
  __shared__ double tot[128];
  int tid = threadIdx.x;
  int col = tid & 127, chunk = tid >> 7;
  double a = 0.0;
  for (int b = chunk; b < NBLKM; b += 8) a += (double)part[b * 128 + col];
  sh[tid] = a;
  __syncthreads();
  if (tid < 128) {
    double v = 0.0;
#pragma unroll
    for (int k = 0; k < 8; ++k) v += sh[k * 128 + tid];
    tot[tid] = v;
  }
  __syncthreads();
  if (tid < 64) {
    double mean = tot[tid] / (double)NN;
    double var = tot[64 + tid] / (double)NN - mean * mean;
    double sc = (double)gma[tid] / sqrt(var + 1e-5);
    ss[tid] = (float)sc;
    ss[64 + tid] = (float)((double)bta[tid] - mean * sc);
  }
}

// ---------------------------------------------------------------- pool + fc
__global__ __launch_bounds__(64) void pool_fc(
    const float* __restrict__ r3, const float* __restrict__ ss,
    const float* __restrict__ wfc, const float* __restrict__ bfc,
    float* __restrict__ out) {
  int g = blockIdx.x, c = threadIdx.x;
  const float* base = r3 + (size_t)g * NPG * 64;
  float s = 0.f;
#pragma unroll
  for (int n = 0; n < NPG; ++n) s += base[n * 64 + c];
  float pooled = fmaf(ss[c], s, (float)NPG * ss[64 + c]);
#pragma unroll
  for (int j = 0; j < 3; ++j) {
    float v = pooled * wfc[c * 3 + j];
    for (int m = 32; m; m >>= 1) v += __shfl_xor(v, m);
    if (c == 0) out[g * 3 + j] = v + bfc[j];
  }
}

// ---------------------------------------------------------------- launch
extern "C" void kernel_launch(void* const* d_in, const int* in_sizes, int n_in,
                              void* d_out, int out_size, void* d_ws, size_t ws_size,
                              hipStream_t stream) {
  const float* x    = (const float*)d_in[0];
  const int*   srcE = (const int*)d_in[1];
  const int*   dstE = (const int*)d_in[2];
  const float* W1a = (const float*)d_in[4],  *b1a = (const float*)d_in[5];
  const float* W1b = (const float*)d_in[6],  *b1b = (const float*)d_in[7];
  const float* g1  = (const float*)d_in[8],  *be1 = (const float*)d_in[9];
  const float* W2a = (const float*)d_in[10], *b2a = (const float*)d_in[11];
  const float* W2b = (const float*)d_in[12], *b2b = (const float*)d_in[13];
  const float* g2  = (const float*)d_in[14], *be2 = (const float*)d_in[15];
  const float* W3a = (const float*)d_in[16], *b3a = (const float*)d_in[17];
  const float* W3b = (const float*)d_in[18], *b3b = (const float*)d_in[19];
  const float* g3  = (const float*)d_in[20], *be3 = (const float*)d_in[21];
  const float* Wfc = (const float*)d_in[22], *bfc = (const float*)d_in[23];

  float* ws = (float*)d_ws;
  float*    Rf     = ws + OFF_R;                 // fp32 view (layer 3 out)
  ushort_t* Rb     = (ushort_t*)(ws + OFF_R);    // bf16 view (layers 1/2 out)
  void*     AGGBF  = (void*)(ws + OFF_AGGBF);
  uint2*    RECS   = (uint2*)(ws + OFF_AGGBF);
  int*      CSR    = (int*)(ws + OFF_CSR);
  int*      CNT    = (int*)(ws + OFF_CNT);
  int*      OFFA   = (int*)(ws + OFF_OFFA);
  int*      BCUR   = (int*)(ws + OFF_BCUR);
  int*      BSTART = (int*)(ws + OFF_BSTART);
  float*    PART   = ws + OFF_PART;
  float*    WT     = ws + OFF_WT;
  ushort_t* WTB    = (ushort_t*)(ws + OFF_WTB);
  float*    SS     = ws + OFF_SS;

  prep_weights<<<6, 256, 0, stream>>>(W1a, W1b, W2a, W2b, W3a, W3b, WT, WTB);

  // ---- CSR build (bucket sort, atomic-light)
  hipMemsetAsync(BCUR, 0, 256 * sizeof(int), stream);
  p3_bin<<<P3BLK, 256, 0, stream>>>(srcE, dstE, BCUR, RECS);
  p_scan248<<<1, 256, 0, stream>>>(BCUR, BSTART);
  p4_build<<<NB, 1024, 0, stream>>>(RECS, BCUR, BSTART, CSR, CNT, OFFA);

  // ---- layer 1
  gather1<<<NN / 256, 256, 0, stream>>>((const float4*)x, CSR, OFFA, CNT,
                                        (float4*)AGGBF);
  mlp_mfma<true, true><<<NBLKM, 256, 0, stream>>>(AGGBF, nullptr, WT, b1a,
                                                  WTB + WB_W1B, b1b,
                                                  nullptr, Rb, PART);
  finalize<<<1, 1024, 0, stream>>>(PART, g1, be1, SS + 0);

  // ---- layer 2
  gather64<<<NN / 4, 256, 0, stream>>>(Rb, CSR, OFFA, CNT, SS + 0,
                                       (ushort_t*)AGGBF);
  mlp_mfma<false, true><<<NBLKM, 256, 0, stream>>>(AGGBF, WTB + WB_W2A, nullptr,
                                                   b2a, WTB + WB_W2B, b2b,
                                                   nullptr, Rb, PART);
  finalize<<<1, 1024, 0, stream>>>(PART, g2, be2, SS + 128);

  // ---- layer 3
  gather64<<<NN / 4, 256, 0, stream>>>(Rb, CSR, OFFA, CNT, SS + 128,
                                       (ushort_t*)AGGBF);
  mlp_mfma<false, false><<<NBLKM, 256, 0, stream>>>(AGGBF, WTB + WB_W3A, nullptr,
                                                    b3a, WTB + WB_W3B, b3b,
                                                    Rf, nullptr, PART);
  finalize<<<1, 1024, 0, stream>>>(PART, g3, be3, SS + 256);

  // ---- pool + classifier
  pool_fc<<<NG, 64, 0, stream>>>(Rf, SS + 256, Wfc, bfc, (float*)d_out);
}

// Round 6
// 877.686 us; speedup vs baseline: 4.6725x; 1.0079x over previous
//
#include <hip/hip_runtime.h>
#include <hip/hip_bf16.h>

// Problem constants (fixed by the reference)
#define NN   507904          // nodes = 8192*62
#define NE   4063232         // edges = NN*8
#define NG   8192            // graphs
#define NPG  62              // nodes per graph
#define NBLKM 992            // NN/512 (mlp grid)

// Bucket sort parameters
#define NB    248            // buckets = NN/2048 (exact)
#define BRNG  2048           // nodes per bucket (bucket = dst>>11)
#define BCAP  17152          // bucket record capacity (mean 16384, +6 sigma)
#define PBCAP 31744          // padded csr capacity/bucket (BCAP + 7*2048, 8-aligned)
#define P3BLK 992            // NE/4096 (exact)
#define CSRSZ (NB * PBCAP)   // 7,872,512 ints

// ---------------------------------------------------------------- ws layout (4B units)
#define OFF_R     0                          // NN*64 units; bf16 rows (NN+1 incl sentinel) or fp32 L3 out
#define OFF_AGGBF (OFF_R + NN * 64)          // t: bf16 NN*64 | aliased: RECS (8.5M units)
#define OFF_CSR   (OFF_AGGBF + NN * 32)      // CSRSZ ints (padded CSR)
#define OFF_CNT   (OFF_CSR + CSRSZ)          // NN ints (actual degree)
#define OFF_OFFA  (OFF_CNT + NN)             // NN ints (padded start offsets)
#define OFF_BCUR  (OFF_OFFA + NN)            // 256 ints
#define OFF_PART  (OFF_BCUR + 256)           // NBLKM*128 floats
#define OFF_WT    (OFF_PART + NBLKM * 128)   // fp32 W1a^T: 256 floats
#define OFF_WTB   (OFF_WT + 256)             // bf16 transposed weights
#define OFF_SS    (OFF_WTB + 10240)          // 3 x (scale[64], shift[64])
// total ~= 57.8M units ~= 231 MB

// bf16 weight offsets (ushort units)
#define WB_W1B 0
#define WB_W2A 4096
#define WB_W2B 8192
#define WB_W3A 12288
#define WB_W3B 16384

typedef __attribute__((ext_vector_type(8))) short short8;
typedef __attribute__((ext_vector_type(4))) float f32x4;
typedef unsigned short ushort_t;

__device__ __forceinline__ ushort_t f2bf_bits(float f) {
  union { float f; unsigned u; } x; x.f = f;
  unsigned r = x.u + 0x7FFF + ((x.u >> 16) & 1);
  return (ushort_t)(r >> 16);
}
__device__ __forceinline__ float bf_lo(unsigned u) {
  union { unsigned i; float f; } x; x.i = u << 16; return x.f;
}
__device__ __forceinline__ float bf_hi(unsigned u) {
  union { unsigned i; float f; } x; x.i = u & 0xFFFF0000u; return x.f;
}

// ---------------------------------------------------------------- weight prep
__global__ __launch_bounds__(256) void prep_weights(
    const float* __restrict__ w1a, const float* __restrict__ w1b,
    const float* __restrict__ w2a, const float* __restrict__ w2b,
    const float* __restrict__ w3a, const float* __restrict__ w3b,
    float* __restrict__ wt, ushort_t* __restrict__ wtb) {
  int b = blockIdx.x, tid = threadIdx.x;
  if (b == 0) {
    if (tid < 256) {
      int k = tid >> 6, n = tid & 63;          // src [4][64]
      wt[n * 4 + k] = w1a[tid];
    }
  } else {
    const float* s; ushort_t* d;
    switch (b) {
      case 1: s = w1b; d = wtb + WB_W1B; break;
      case 2: s = w2a; d = wtb + WB_W2A; break;
      case 3: s = w2b; d = wtb + WB_W2B; break;
      case 4: s = w3a; d = wtb + WB_W3A; break;
      default: s = w3b; d = wtb + WB_W3B; break;
    }
    for (int i = tid; i < 4096; i += 256) {
      int k = i >> 6, n = i & 63;              // src [k][n]
      d[n * 64 + k] = f2bf_bits(s[i]);         // dst [n][k]
    }
  }
}

// ---------------------------------------------------------------- CSR build: phase 1
__global__ __launch_bounds__(256) void p3_bin(
    const int* __restrict__ src, const int* __restrict__ dst,
    int* __restrict__ bcur, uint2* __restrict__ recs) {
  __shared__ int histo[256];
  __shared__ int scan_s[256];
  __shared__ int base_s[256];
  __shared__ int cur_s[256];
  __shared__ uint2 buf[4096];
  const int tid = threadIdx.x;
  const int e0 = blockIdx.x * 4096;

  histo[tid] = 0;
  __syncthreads();

  int d_[16], s_[16];
#pragma unroll
  for (int k = 0; k < 16; ++k) {
    int e = e0 + k * 256 + tid;
    d_[k] = dst[e]; s_[k] = src[e];
    atomicAdd(&histo[d_[k] >> 11], 1);
  }
  __syncthreads();

  int v = histo[tid];
  scan_s[tid] = v; __syncthreads();
  for (int s = 1; s < 256; s <<= 1) {
    int add = (tid >= s) ? scan_s[tid - s] : 0;
    __syncthreads();
    scan_s[tid] += add;
    __syncthreads();
  }
  int excl = scan_s[tid] - v;
  if (tid < NB) base_s[tid] = atomicAdd(&bcur[tid], v);
  cur_s[tid] = excl;
  histo[tid] = excl;
  __syncthreads();

#pragma unroll
  for (int k = 0; k < 16; ++k) {
    int b = d_[k] >> 11;
    int p = atomicAdd(&cur_s[b], 1);
    uint2 r; r.x = (unsigned)d_[k]; r.y = (unsigned)s_[k];
    buf[p] = r;
  }
  __syncthreads();

  for (int i = tid; i < 4096; i += 256) {
    uint2 r = buf[i];
    int b = (int)(r.x >> 11);
    int g = base_s[b] + (i - histo[b]);
    if (g < BCAP) recs[(size_t)b * BCAP + g] = r;
  }
}

// ---------------------------------------------------------------- CSR build: phase 2
// One workgroup per bucket. Padded CSR: each node's list 8-aligned, padded
// with sentinel NN. Bucket b owns csr[b*PBCAP ...].
__global__ __launch_bounds__(1024) void p4_build(
    const uint2* __restrict__ recs, const int* __restrict__ bcur,
    int* __restrict__ csr, int* __restrict__ cnt, int* __restrict__ offa) {
  __shared__ int lcnt[2048];
  __shared__ int pscan[1024];
  __shared__ int sstart[2048];   // padded start (stable)
  __shared__ int scur[2048];     // placement cursors
  const int b = blockIdx.x, tid = threadIdx.x;
  int m = bcur[b]; if (m > BCAP) m = BCAP;
  const int cbase = b * PBCAP;
  const int nbase = b << 11;
  const uint2* rp = recs + (size_t)b * BCAP;

  lcnt[tid] = 0; lcnt[1024 + tid] = 0;
  __syncthreads();
  for (int i = tid; i < m; i += 1024)
    atomicAdd(&lcnt[rp[i].x & (BRNG - 1)], 1);
  __syncthreads();

  int a0 = lcnt[2 * tid], a1 = lcnt[2 * tid + 1];
  int p0 = (a0 + 7) & ~7, p1 = (a1 + 7) & ~7;
  int ps = p0 + p1;
  pscan[tid] = ps; __syncthreads();
  for (int s = 1; s < 1024; s <<= 1) {
    int add = (tid >= s) ? pscan[tid - s] : 0;
    __syncthreads();
    pscan[tid] += add;
    __syncthreads();
  }
  int e0 = pscan[tid] - ps;
  sstart[2 * tid] = e0;       scur[2 * tid] = e0;
  sstart[2 * tid + 1] = e0 + p0; scur[2 * tid + 1] = e0 + p0;
  __syncthreads();

  cnt[nbase + tid] = lcnt[tid];
  cnt[nbase + 1024 + tid] = lcnt[1024 + tid];
  offa[nbase + tid] = cbase + sstart[tid];
  offa[nbase + 1024 + tid] = cbase + sstart[1024 + tid];
  __syncthreads();

  for (int i = tid; i < m; i += 1024) {
    uint2 r = rp[i];
    int p = atomicAdd(&scur[r.x & (BRNG - 1)], 1);
    csr[cbase + p] = (int)r.y;
  }
  __syncthreads();

  // sentinel pad fill
#pragma unroll
  for (int k = 0; k < 2; ++k) {
    int i = k * 1024 + tid;
    int st = sstart[i], d = lcnt[i], p = (d + 7) & ~7;
    for (int q = d; q < p; ++q) csr[cbase + st + q] = NN;
  }
}

// ---------------------------------------------------------------- gather L1 (C=4)
__global__ __launch_bounds__(256) void gather1(
    const float4* __restrict__ x, const int* __restrict__ csr,
    const int* __restrict__ offa, const int* __restrict__ cnt,
    float4* __restrict__ tout) {
  int n = blockIdx.x * 256 + threadIdx.x;
  float4 a = x[n];
  int off = offa[n], deg = cnt[n];
  const int* cp = csr + off;
  int j = 0;
  for (; j + 4 <= deg; j += 4) {
    int s0 = cp[j], s1 = cp[j + 1], s2 = cp[j + 2], s3 = cp[j + 3];
    float4 v0 = x[s0], v1 = x[s1], v2 = x[s2], v3 = x[s3];
    a.x += v0.x + v1.x + v2.x + v3.x;
    a.y += v0.y + v1.y + v2.y + v3.y;
    a.z += v0.z + v1.z + v2.z + v3.z;
    a.w += v0.w + v1.w + v2.w + v3.w;
  }
  for (; j < deg; ++j) {
    float4 v = x[cp[j]];
    a.x += v.x; a.y += v.y; a.z += v.z; a.w += v.w;
  }
  tout[n] = a;
}

// ---------------------------------------------------------------- gather L2/3 (C=64, bf16 rows)
// Wave per node. 8-lane groups: group g loads padded-neighbor g's row as
// uint4 (1 KB/wave-instruction); butterfly-sum across groups; affine after
// sum: t = sc*(self+sum) + (deg+1)*sf (pad rows are zero, contribute nothing).
__global__ __launch_bounds__(256) void gather64v2(
    const ushort_t* __restrict__ h, const int* __restrict__ csr,
    const int* __restrict__ offa, const int* __restrict__ cnt,
    const float* __restrict__ ss, ushort_t* __restrict__ tout) {
  const int lane = threadIdx.x & 63;
  const int n = blockIdx.x * 4 + (threadIdx.x >> 6);
  const int g = lane >> 3, sub = lane & 7;
  const int deg = cnt[n];
  const int off = offa[n];
  const int chunks = (deg + 7) >> 3;

  float acc[8] = {0.f, 0.f, 0.f, 0.f, 0.f, 0.f, 0.f, 0.f};
  for (int c = 0; c < chunks; ++c) {
    int row = csr[off + (c << 3) + g];
    uint4 u = *(const uint4*)(h + (size_t)row * 64 + (sub << 3));
    acc[0] += bf_lo(u.x); acc[1] += bf_hi(u.x);
    acc[2] += bf_lo(u.y); acc[3] += bf_hi(u.y);
    acc[4] += bf_lo(u.z); acc[5] += bf_hi(u.z);
    acc[6] += bf_lo(u.w); acc[7] += bf_hi(u.w);
  }
#pragma unroll
  for (int j = 0; j < 8; ++j) {
    acc[j] += __shfl_xor(acc[j], 8);
    acc[j] += __shfl_xor(acc[j], 16);
    acc[j] += __shfl_xor(acc[j], 32);
  }

  if (g == 0) {
    uint4 u = *(const uint4*)(h + (size_t)n * 64 + (sub << 3));
    acc[0] += bf_lo(u.x); acc[1] += bf_hi(u.x);
    acc[2] += bf_lo(u.y); acc[3] += bf_hi(u.y);
    acc[4] += bf_lo(u.z); acc[5] += bf_hi(u.z);
    acc[6] += bf_lo(u.w); acc[7] += bf_hi(u.w);
    const float m1 = (float)(deg + 1);
    const float4* scp = (const float4*)(ss + (sub << 3));
    const float4* sfp = (const float4*)(ss + 64 + (sub << 3));
    float4 sc0 = scp[0], sc1 = scp[1];
    float4 sf0 = sfp[0], sf1 = sfp[1];
    float t0 = fmaf(sc0.x, acc[0], m1 * sf0.x);
    float t1 = fmaf(sc0.y, acc[1], m1 * sf0.y);
    float t2 = fmaf(sc0.z, acc[2], m1 * sf0.z);
    float t3 = fmaf(sc0.w, acc[3], m1 * sf0.w);
    float t4 = fmaf(sc1.x, acc[4], m1 * sf1.x);
    float t5 = fmaf(sc1.y, acc[5], m1 * sf1.y);
    float t6 = fmaf(sc1.z, acc[6], m1 * sf1.z);
    float t7 = fmaf(sc1.w, acc[7], m1 * sf1.w);
    uint4 o;
    o.x = ((unsigned)f2bf_bits(t1) << 16) | f2bf_bits(t0);
    o.y = ((unsigned)f2bf_bits(t3) << 16) | f2bf_bits(t2);
    o.z = ((unsigned)f2bf_bits(t5) << 16) | f2bf_bits(t4);
    o.w = ((unsigned)f2bf_bits(t7) << 16) | f2bf_bits(t6);
    *(uint4*)(tout + (size_t)n * 64 + (sub << 3)) = o;
  }
}

// ---------------------------------------------------------------- MFMA MLP
template <bool L1, bool BFOUT>
__global__ __launch_bounds__(256) void mlp_mfma(
    const void* __restrict__ tin,
    const ushort_t* __restrict__ WaTb,
    const float* __restrict__ WaTf,
    const float* __restrict__ ba,
    const ushort_t* __restrict__ WbTb,
    const float* __restrict__ bb,
    float* __restrict__ routf, ushort_t* __restrict__ routb,
    float* __restrict__ part) {
  __shared__ __align__(16) ushort_t zt[4096];
  __shared__ float red[512];
  __shared__ float wa_l1[320];
  const int tid = threadIdx.x;
  const int wave = tid >> 6, lane = tid & 63;
  const int col = lane & 15, quad = lane >> 4;

  if (L1) {
    if (tid < 256) wa_l1[tid] = WaTf[tid];
    if (tid < 64) wa_l1[256 + tid] = ba[tid];
    __syncthreads();
  }

  short8 bWa[2][4], bWb[2][4];
#pragma unroll
  for (int k0 = 0; k0 < 2; ++k0)
#pragma unroll
    for (int nt = 0; nt < 4; ++nt) {
      if (!L1) bWa[k0][nt] = *(const short8*)(WaTb + (nt * 16 + col) * 64 + k0 * 32 + quad * 8);
      bWb[k0][nt] = *(const short8*)(WbTb + (nt * 16 + col) * 64 + k0 * 32 + quad * 8);
    }
  float ba_n[4], bb_n[4];
#pragma unroll
  for (int nt = 0; nt < 4; ++nt) {
    if (!L1) ba_n[nt] = ba[nt * 16 + col];
    bb_n[nt] = bb[nt * 16 + col];
  }

  const int wbase = wave * 1024;
  float scol[4] = {0, 0, 0, 0}, qcol[4] = {0, 0, 0, 0};

  for (int it = 0; it < 8; ++it) {
    const int tile = blockIdx.x * 512 + it * 64 + wave * 16;
    short8 az0, az1;

    if constexpr (L1) {
      float4 t4 = ((const float4*)tin)[tile + col];
#pragma unroll
      for (int k0 = 0; k0 < 2; ++k0) {
        short8 az;
#pragma unroll
        for (int j = 0; j < 8; ++j) {
          int o = k0 * 32 + quad * 8 + j;
          float z = wa_l1[256 + o];
          z = fmaf(t4.x, wa_l1[o * 4 + 0], z);
          z = fmaf(t4.y, wa_l1[o * 4 + 1], z);
          z = fmaf(t4.z, wa_l1[o * 4 + 2], z);
          z = fmaf(t4.w, wa_l1[o * 4 + 3], z);
          az[j] = (short)f2bf_bits(fmaxf(z, 0.0f));
        }
        if (k0 == 0) az0 = az; else az1 = az;
      }
    } else {
      const ushort_t* tb = (const ushort_t*)tin;
      short8 a0 = *(const short8*)(tb + (size_t)(tile + col) * 64 + quad * 8);
      short8 a1 = *(const short8*)(tb + (size_t)(tile + col) * 64 + 32 + quad * 8);
      f32x4 acc1[4];
#pragma unroll
      for (int nt = 0; nt < 4; ++nt) acc1[nt] = (f32x4){0.f, 0.f, 0.f, 0.f};
#pragma unroll
      for (int nt = 0; nt < 4; ++nt) {
        acc1[nt] = __builtin_amdgcn_mfma_f32_16x16x32_bf16(a0, bWa[0][nt], acc1[nt], 0, 0, 0);
        acc1[nt] = __builtin_amdgcn_mfma_f32_16x16x32_bf16(a1, bWa[1][nt], acc1[nt], 0, 0, 0);
      }
#pragma unroll
      for (int nt = 0; nt < 4; ++nt) {
        int oblk = nt * 2 + (col >> 3);
#pragma unroll
        for (int r = 0; r < 4; ++r) {
          int row = quad * 4 + r;
          float z = fmaxf(acc1[nt][r] + ba_n[nt], 0.0f);
          zt[wbase + row * 64 + (((oblk ^ (row & 7)) << 3) | (col & 7))] = f2bf_bits(z);
        }
      }
      int m = col;
      az0 = *(const short8*)&zt[wbase + m * 64 + ((quad ^ (m & 7)) << 3)];
      az1 = *(const short8*)&zt[wbase + m * 64 + (((4 + quad) ^ (m & 7)) << 3)];
    }

    f32x4 acc2[4];
#pragma unroll
    for (int nt = 0; nt < 4; ++nt) acc2[nt] = (f32x4){0.f, 0.f, 0.f, 0.f};
#pragma unroll
    for (int nt = 0; nt < 4; ++nt) {
      acc2[nt] = __builtin_amdgcn_mfma_f32_16x16x32_bf16(az0, bWb[0][nt], acc2[nt], 0, 0, 0);
      acc2[nt] = __builtin_amdgcn_mfma_f32_16x16x32_bf16(az1, bWb[1][nt], acc2[nt], 0, 0, 0);
    }
#pragma unroll
    for (int nt = 0; nt < 4; ++nt) {
#pragma unroll
      for (int r = 0; r < 4; ++r) {
        int row = tile + quad * 4 + r;
        float v = fmaxf(acc2[nt][r] + bb_n[nt], 0.0f);
        if (BFOUT) routb[(size_t)row * 64 + nt * 16 + col] = f2bf_bits(v);
        else       routf[(size_t)row * 64 + nt * 16 + col] = v;
        scol[nt] += v; qcol[nt] += v * v;
      }
    }
  }

#pragma unroll
  for (int nt = 0; nt < 4; ++nt) {
    float s = scol[nt], q = qcol[nt];
    s += __shfl_xor(s, 16); s += __shfl_xor(s, 32);
    q += __shfl_xor(q, 16); q += __shfl_xor(q, 32);
    if (quad == 0) {
      red[wave * 128 + nt * 16 + col] = s;
      red[wave * 128 + 64 + nt * 16 + col] = q;
    }
  }
  __syncthreads();
  if (tid < 128)
    part[blockIdx.x * 128 + tid] =
        red[tid] + red[128 + tid] + red[256 + tid] + red[384 + tid];
}

// ---------------------------------------------------------------- BN finalize
__global__ __launch_bounds__(1024) void finalize(
    const float* __restrict__ part, const float* __restrict__ gma,
    const float* __restrict__ bta, float* __restrict__ ss) {
  __shared__ double sh[1024];
  __shared__ double tot[128];
  int tid = threadIdx.x;
  int col = tid & 127, chunk = tid >> 7;
  double a = 0.0;
  for (int b = chunk; b < NBLKM; b += 8) a += (double)part[b * 128 + col];
  sh[tid] = a;
  __syncthreads();
  if (tid < 128) {
    double v = 0.0;
#pragma unroll
    for (int k = 0; k < 8; ++k) v += sh[k * 128 + tid];
    tot[tid] = v;
  }
  __syncthreads();
  if (tid < 64) {
    double mean = tot[tid] / (double)NN;
    double var = tot[64 + tid] / (double)NN - mean * mean;
    double sc = (double)gma[tid] / sqrt(var + 1e-5);
    ss[tid] = (float)sc;
    ss[64 + tid] = (float)((double)bta[tid] - mean * sc);
  }
}

// ---------------------------------------------------------------- pool + fc
__global__ __launch_bounds__(64) void pool_fc(
    const float* __restrict__ r3, const float* __restrict__ ss,
    const float* __restrict__ wfc, const float* __restrict__ bfc,
    float* __restrict__ out) {
  int g = blockIdx.x, c = threadIdx.x;
  const float* base = r3 + (size_t)g * NPG * 64;
  float s = 0.f;
#pragma unroll
  for (int n = 0; n < NPG; ++n) s += base[n * 64 + c];
  float pooled = fmaf(ss[c], s, (float)NPG * ss[64 + c]);
#pragma unroll
  for (int j = 0; j < 3; ++j) {
    float v = pooled * wfc[c * 3 + j];
    for (int m = 32; m; m >>= 1) v += __shfl_xor(v, m);
    if (c == 0) out[g * 3 + j] = v + bfc[j];
  }
}

// ---------------------------------------------------------------- launch
extern "C" void kernel_launch(void* const* d_in, const int* in_sizes, int n_in,
                              void* d_out, int out_size, void* d_ws, size_t ws_size,
                              hipStream_t stream) {
  const float* x    = (const float*)d_in[0];
  const int*   srcE = (const int*)d_in[1];
  const int*   dstE = (const int*)d_in[2];
  const float* W1a = (const float*)d_in[4],  *b1a = (const float*)d_in[5];
  const float* W1b = (const float*)d_in[6],  *b1b = (const float*)d_in[7];
  const float* g1  = (const float*)d_in[8],  *be1 = (const float*)d_in[9];
  const float* W2a = (const float*)d_in[10], *b2a = (const float*)d_in[11];
  const float* W2b = (const float*)d_in[12], *b2b = (const float*)d_in[13];
  const float* g2  = (const float*)d_in[14], *be2 = (const float*)d_in[15];
  const float* W3a = (const float*)d_in[16], *b3a = (const float*)d_in[17];
  const float* W3b = (const float*)d_in[18], *b3b = (const float*)d_in[19];
  const float* g3  = (const float*)d_in[20], *be3 = (const float*)d_in[21];
  const float* Wfc = (const float*)d_in[22], *bfc = (const float*)d_in[23];

  float* ws = (float*)d_ws;
  float*    Rf     = ws + OFF_R;                 // fp32 view (layer 3 out)
  ushort_t* Rb     = (ushort_t*)(ws + OFF_R);    // bf16 view (layers 1/2 out + sentinel row NN)
  void*     AGGBF  = (void*)(ws + OFF_AGGBF);
  uint2*    RECS   = (uint2*)(ws + OFF_AGGBF);
  int*      CSR    = (int*)(ws + OFF_CSR);
  int*      CNT    = (int*)(ws + OFF_CNT);
  int*      OFFA   = (int*)(ws + OFF_OFFA);
  int*      BCUR   = (int*)(ws + OFF_BCUR);
  float*    PART   = ws + OFF_PART;
  float*    WT     = ws + OFF_WT;
  ushort_t* WTB    = (ushort_t*)(ws + OFF_WTB);
  float*    SS     = ws + OFF_SS;

  prep_weights<<<6, 256, 0, stream>>>(W1a, W1b, W2a, W2b, W3a, W3b, WT, WTB);

  // ---- CSR build (bucket sort, atomic-light, padded to 8 with sentinel NN)
  hipMemsetAsync(BCUR, 0, 256 * sizeof(int), stream);
  hipMemsetAsync(Rb + (size_t)NN * 64, 0, 128, stream);   // sentinel zero row
  p3_bin<<<P3BLK, 256, 0, stream>>>(srcE, dstE, BCUR, RECS);
  p4_build<<<NB, 1024, 0, stream>>>(RECS, BCUR, CSR, CNT, OFFA);

  // ---- layer 1
  gather1<<<NN / 256, 256, 0, stream>>>((const float4*)x, CSR, OFFA, CNT,
                                        (float4*)AGGBF);
  mlp_mfma<true, true><<<NBLKM, 256, 0, stream>>>(AGGBF, nullptr, WT, b1a,
                                                  WTB + WB_W1B, b1b,
                                                  nullptr, Rb, PART);
  finalize<<<1, 1024, 0, stream>>>(PART, g1, be1, SS + 0);

  // ---- layer 2
  gather64v2<<<NN / 4, 256, 0, stream>>>(Rb, CSR, OFFA, CNT, SS + 0,
                                         (ushort_t*)AGGBF);
  mlp_mfma<false, true><<<NBLKM, 256, 0, stream>>>(AGGBF, WTB + WB_W2A, nullptr,
                                                   b2a, WTB + WB_W2B, b2b,
                                                   nullptr, Rb, PART);
  finalize<<<1, 1024, 0, stream>>>(PART, g2, be2, SS + 128);

  // ---- layer 3
  gather64v2<<<NN / 4, 256, 0, stream>>>(Rb, CSR, OFFA, CNT, SS + 128,
                                         (ushort_t*)AGGBF);
  mlp_mfma<false, false><<<NBLKM, 256, 0, stream>>>(AGGBF, WTB + WB_W3A, nullptr,
                                                    b3a, WTB + WB_W3B, b3b,
                                                    Rf, nullptr, PART);
  finalize<<<1, 1024, 0, stream>>>(PART, g3, be3, SS + 256);

  // ---- pool + classifier
  pool_fc<<<NG, 64, 0, stream>>>(Rf, SS + 256, Wfc, bfc, (float*)d_out);
}